// Round 21
// baseline (411.046 us; speedup 1.0000x reference)
//
#include <hip/hip_runtime.h>

#define N_IN 2000000
#define N_OUT 250000
#define C_IN 32
#define C_OUT 64
#define K_VOL 8
#define EPS 1e-5f
#define CAP 32

#define PT_BLOCKS 7813         // ceil(N_IN/256)
#define N_SCAN 250112          // 977*256
#define N_SBLK 977

typedef __attribute__((ext_vector_type(8))) short short8;
typedef __attribute__((ext_vector_type(4))) float f32x4;

// ======== tier-A workspace layout (int units) ========
#define TA_WHL    250368
#define TA_BSUM   266752
#define TA_SMALL  267776
#define TA_CNT    268288
#define TA_IDXG   1018400                                          // idxg[2M]
#define TA_POS    (TA_IDXG + N_IN)                                 // pos0[2M]
#define TA_NEED_BYTES ((size_t)(TA_POS + N_IN) * 4)                // ~20 MB

// ======== tier-B (round-4 validated) workspace layout ========
#define T1_WT     250000
#define T1_SMALL  266384
#define T1_RLIST  266768
#define T1_NEED_BYTES ((size_t)(T1_RLIST + N_OUT * CAP) * 4)

// ==================== tier-A: single-atomic-pass counting sort ====================
// +1 tail block zeroes smalls[128] (consumed much later by k_stats/k_ctxprep).
__global__ __launch_bounds__(256) void k_rank(const int* __restrict__ out_idx,
                                              int* __restrict__ cnt,
                                              int* __restrict__ pos0,
                                              float* __restrict__ smalls) {
    int b = blockIdx.x;
    if (b < PT_BLOCKS) {
        int i = b * 256 + threadIdx.x;
        if (i < N_IN) pos0[i] = atomicAdd(&cnt[out_idx[i]], 1);
    } else {
        if (threadIdx.x < 128) smalls[threadIdx.x] = 0.f;
    }
}

__global__ __launch_bounds__(256) void k_scan_a(const int* __restrict__ cnt,
                                                int* __restrict__ S,
                                                int* __restrict__ bsum) {
    __shared__ int sh[256];
    int t = threadIdx.x;
    int g = blockIdx.x * 256 + t;
    int v = cnt[g];
    sh[t] = v;
    __syncthreads();
#pragma unroll
    for (int off = 1; off < 256; off <<= 1) {
        int a = (t >= off) ? sh[t - off] : 0;
        __syncthreads();
        sh[t] += a;
        __syncthreads();
    }
    S[g] = sh[t] - v;              // exclusive within block
    if (t == 255) bsum[blockIdx.x] = sh[255];
}

// scan_b folded in: each block sums bsum[j < blockIdx] (L2-hot) via tree-reduce.
__global__ __launch_bounds__(256) void k_scan_c2(int* __restrict__ S,
                                                 const int* __restrict__ bsum) {
    __shared__ int red[256];
    int t = threadIdx.x, bid = blockIdx.x;
    int acc = 0;
    for (int j = t; j < bid; j += 256) acc += bsum[j];
    red[t] = acc;
    __syncthreads();
#pragma unroll
    for (int off = 128; off > 0; off >>= 1) {
        if (t < off) red[t] += red[t + off];
        __syncthreads();
    }
    S[bid * 256 + t] += red[0];
}

// Index-only scatter (L2-absorbed 4B writes) + fused weight hi/lo pack tail.
__global__ __launch_bounds__(256) void k_scatidx(const int* __restrict__ out_idx,
                                                 const int* __restrict__ offs,
                                                 const int* __restrict__ pos0,
                                                 const int* __restrict__ S,
                                                 const float* __restrict__ w,
                                                 int* __restrict__ idxg,
                                                 ushort* __restrict__ whl) {
    int b = blockIdx.x;
    if (b < PT_BLOCKS) {
        int i = b * 256 + threadIdx.x;
        if (i >= N_IN) return;
        int o = out_idx[i];
        int tag = offs[i] | ((o & 31) << 3);
        idxg[S[o] + pos0[i]] = i | (tag << 21);
    } else {
        int e = (b - PT_BLOCKS) * 256 + threadIdx.x;   // 0..16383
        int c = e >> 11, t = (e >> 9) & 3, l = (e >> 3) & 63, kp = e & 7;
        int j = 4 * c + (l >> 4);
        int n = t * 16 + (l & 15);
        float v = w[kp * 2048 + j * 64 + n];
        unsigned bits = __float_as_uint(v);
        float lo = v - __uint_as_float(bits & 0xFFFF0000u);
        whl[e]         = (ushort)(bits >> 16);
        whl[16384 + e] = (ushort)(__float_as_uint(lo) >> 16);
    }
}

// ==================== tier-A: gconv12 body at 1 wave/block (12 blocks/CU) ====================
// Identical inner code to validated gconv12; block = 64 threads so per-CU
// resident waves rise 9.3 -> 12 (TLP test: same per-wave work, more waves).
__global__ __launch_bounds__(64) void k_gconv13(const float* __restrict__ xf,
                                                const int* __restrict__ idxg,
                                                const int* __restrict__ Sarr,
                                                const ushort* __restrict__ whl,
                                                float* __restrict__ out) {
    __shared__ float vxl[3104];
    int lane = threadIdx.x & 63;
    int g = blockIdx.x;
    int base = g * 8;
    if (base >= N_OUT) return;
    float* VX = vxl;
    short* XT = (short*)VX;   // 2 staging buffers of 3104 shorts each (alias VX head)

    int s = Sarr[base];
    int e = Sarr[base + 8];
    int slot = lane >> 3, jq = lane & 7;

    int tgt4[4];
#pragma unroll
    for (int m = 0; m < 4; ++m) {
        int bin0 = m * 16 + (lane & 15);
        tgt4[m] = (((base + (bin0 >> 3)) & 31) << 3) | (bin0 & 7);
    }

    f32x4 acc1[4][2];
#pragma unroll
    for (int m = 0; m < 4; ++m)
#pragma unroll
        for (int n = 0; n < 2; ++n)
            acc1[m][n] = (f32x4){0.f, 0.f, 0.f, 0.f};

    auto LOADBLK = [&](int p0, float4* xvv, int* tvv) {
        int pk[4];
#pragma unroll
        for (int q = 0; q < 4; ++q) {
            int p = p0 + q * 8 + slot;
            int pc = p < e ? p : e - 1;
            pk[q] = idxg[pc];                       // coalesced 4B (broadcast in group)
        }
#pragma unroll
        for (int q = 0; q < 4; ++q) {
            int p = p0 + q * 8 + slot;
            int idx = pk[q] & 0x1FFFFF;
            tvv[q] = (pk[q] >> 21) & 0xFF;
            xvv[q] = *(const float4*)(xf + (size_t)idx * 32 + jq * 4);  // full 128B line/group
            if (p >= e) xvv[q] = make_float4(0.f, 0.f, 0.f, 0.f);       // pad adds 0
        }
    };
    auto STAGE = [&](int bb, const float4* xvv, const int* tvv) {
        short* Xh = XT + bb * 3104;
        short* Xl = Xh + 1536;
        unsigned char* TGb = (unsigned char*)(Xh + 3072);
#pragma unroll
        for (int q = 0; q < 4; ++q) {
            int wpos = ((q ^ (jq & 3)) << 3) + slot;   // XOR block swizzle
#pragma unroll
            for (int i = 0; i < 4; ++i) {
                float v = (i == 0) ? xvv[q].x : (i == 1) ? xvv[q].y
                         : (i == 2) ? xvv[q].z : xvv[q].w;
                unsigned b = __float_as_uint(v);
                float lo = v - __uint_as_float(b & 0xFFFF0000u);
                int ch = 4 * jq + i;
                Xh[ch * 48 + wpos] = (short)(b >> 16);
                Xl[ch * 48 + wpos] = (short)(__float_as_uint(lo) >> 16);
            }
            if (jq == 0) TGb[q * 8 + slot] = (unsigned char)tvv[q];
        }
    };

    if (e > s) {
        float4 xvA[4], xvB[4], xvC[4];
        int tvA[4], tvB[4], tvC[4];
        int nIt = (e - s + 31) >> 5;
        LOADBLK(s, xvA, tvA);                    // it 0
        LOADBLK(s + 32, xvB, tvB);               // it 1 (clamped if absent)
        STAGE(0, xvA, tvA);
        for (int it = 0; it < nIt; ++it) {
            int cur = it & 1;
            if (it + 2 < nIt) LOADBLK(s + (it + 2) * 32, xvC, tvC);  // 2-deep prefetch

            asm volatile("s_waitcnt lgkmcnt(0)" ::: "memory");  // stage(cur) drained

            const short* Xh = XT + cur * 3104;
            const short* Xl = Xh + 1536;
            const unsigned char* TGb = (const unsigned char*)(Xh + 3072);
            unsigned long long t8 = *(const unsigned long long*)(TGb + 8 * (lane >> 4));
            int tgv[8];
#pragma unroll
            for (int e2 = 0; e2 < 8; ++e2) tgv[e2] = (int)((t8 >> (8 * e2)) & 0xFF);
            short8 bhf[2], blf[2];
#pragma unroll
            for (int n = 0; n < 2; ++n) {
                int ch = n * 16 + (lane & 15);
                int off = ch * 48 + 8 * ((lane >> 4) ^ ((ch >> 2) & 3));
                bhf[n] = *(const short8*)(Xh + off);
                blf[n] = *(const short8*)(Xl + off);
            }

            // ---- issue next-buffer STAGE writes BEFORE MFMA (overlap) ----
            if (it + 1 < nIt) STAGE(cur ^ 1, xvB, tvB);
            __builtin_amdgcn_sched_barrier(0);   // pin: writes issue before MFMA

#pragma unroll
            for (int m = 0; m < 4; ++m) {
                short8 ah;
#pragma unroll
                for (int e2 = 0; e2 < 8; ++e2)
                    ah[e2] = (tgv[e2] == tgt4[m]) ? (short)0x3F80 : (short)0;
#pragma unroll
                for (int n = 0; n < 2; ++n) {
                    acc1[m][n] = __builtin_amdgcn_mfma_f32_16x16x32_bf16(ah, bhf[n], acc1[m][n], 0, 0, 0);
                    acc1[m][n] = __builtin_amdgcn_mfma_f32_16x16x32_bf16(ah, blf[n], acc1[m][n], 0, 0, 0);
                }
            }

            if (it + 1 < nIt) {
#pragma unroll
                for (int q = 0; q < 4; ++q) { xvB[q] = xvC[q]; tvB[q] = tvC[q]; }
            }
        }
    }

    asm volatile("s_waitcnt lgkmcnt(0)" ::: "memory");

    // ---- deposit XS -> VX[r*289 + ch*9 + kp] (r in 0..7, full coverage) ----
#pragma unroll
    for (int m = 0; m < 4; ++m)
#pragma unroll
        for (int n = 0; n < 2; ++n)
#pragma unroll
            for (int reg = 0; reg < 4; ++reg) {
                int bin = m * 16 + (lane >> 4) * 4 + reg;     // 0..63
                VX[(bin >> 3) * 289 + (n * 16 + (lane & 15)) * 9 + (bin & 7)] = acc1[m][n][reg];
            }

    __builtin_amdgcn_sched_barrier(0);
    asm volatile("s_waitcnt lgkmcnt(0)" ::: "memory");
    __builtin_amdgcn_sched_barrier(0);

    // ---- GEMM-2: out[8x64] = XS[8x256] @ W[256x64], split-bf16, M padded to 16 ----
    int o = lane >> 4;
    int n16 = lane & 15;
    f32x4 zacc = {0.f, 0.f, 0.f, 0.f};
    f32x4 acc0 = zacc, accA = zacc, accB = zacc, accC = zacc;
    const short8* wh = (const short8*)whl;
    const short8* wl = wh + 2048;

#pragma unroll
    for (int c = 0; c < 8; ++c) {
        float a[8];
        if (n16 < 8) {
            const float* src = VX + n16 * 289 + (4 * c + o) * 9;
#pragma unroll
            for (int el = 0; el < 8; ++el) a[el] = src[el];
        } else {
#pragma unroll
            for (int el = 0; el < 8; ++el) a[el] = 0.f;
        }
        short8 ahi, alo;
#pragma unroll
        for (int el = 0; el < 8; ++el) {
            unsigned b = __float_as_uint(a[el]);
            ahi[el] = (short)(b >> 16);
            float lo = a[el] - __uint_as_float(b & 0xFFFF0000u);
            alo[el] = (short)(__float_as_uint(lo) >> 16);
        }
#pragma unroll
        for (int t = 0; t < 4; ++t) {
            short8 bh = wh[(c * 4 + t) * 64 + lane];
            short8 bl = wl[(c * 4 + t) * 64 + lane];
            f32x4* pa = (t == 0) ? &acc0 : (t == 1) ? &accA : (t == 2) ? &accB : &accC;
            *pa = __builtin_amdgcn_mfma_f32_16x16x32_bf16(ahi, bh, *pa, 0, 0, 0);
            *pa = __builtin_amdgcn_mfma_f32_16x16x32_bf16(alo, bh, *pa, 0, 0, 0);
            *pa = __builtin_amdgcn_mfma_f32_16x16x32_bf16(ahi, bl, *pa, 0, 0, 0);
        }
    }

    if (o < 2) {                                   // D rows 0..7 only
#pragma unroll
        for (int t = 0; t < 4; ++t) {
            f32x4 a = (t == 0) ? acc0 : (t == 1) ? accA : (t == 2) ? accB : accC;
#pragma unroll
            for (int reg = 0; reg < 4; ++reg)
                out[(size_t)(base + o * 4 + reg) * 64 + t * 16 + n16] = a[reg];
        }
    }
}

// ==================== shared post-passes ====================

__global__ __launch_bounds__(256) void k_stats(const float* __restrict__ out,
                                               float* __restrict__ sums,
                                               float* __restrict__ sumsq) {
    int t = threadIdx.x;
    long stride = (long)gridDim.x * 256;
    float s = 0.f, q = 0.f;
    for (long i = (long)blockIdx.x * 256 + t; i < (long)N_OUT * C_OUT; i += stride) {
        float v = out[i];
        s += v;
        q = fmaf(v, v, q);
    }
    __shared__ float ls[256], lq[256];
    ls[t] = s; lq[t] = q;
    __syncthreads();
    if (t < 64) {
        s = ls[t] + ls[t + 64] + ls[t + 128] + ls[t + 192];
        q = lq[t] + lq[t + 64] + lq[t + 128] + lq[t + 192];
        atomicAdd(&sums[t], s);
        atomicAdd(&sumsq[t], q);
    }
}

__global__ __launch_bounds__(256) void k_ctxprep(const float* __restrict__ context,
                                                 const float* __restrict__ ctx_w,
                                                 const float* __restrict__ sums,
                                                 const float* __restrict__ sumsq,
                                                 const float* __restrict__ gamma,
                                                 const float* __restrict__ beta,
                                                 const int* __restrict__ cond,
                                                 float* __restrict__ AB) {
    __shared__ float part[256];
    __shared__ float ctxv[128];
    int t = threadIdx.x;
    int col = t & 127, half = t >> 7;
    float s = 0.f;
    for (int r = half * 128; r < half * 128 + 128; ++r)
        s = fmaf(context[r], ctx_w[r * 128 + col], s);
    part[t] = s;
    __syncthreads();
    if (t < 128) ctxv[t] = part[t] + part[t + 128];
    __syncthreads();
    if (t < 64) {
        float mean = sums[t] * (1.f / N_OUT);
        float var  = sumsq[t] * (1.f / N_OUT) - mean * mean;
        float inv  = rsqrtf(var + EPS);
        int cd = cond[0];
        float gm = gamma[cd * C_OUT + t], bt = beta[cd * C_OUT + t];
        float sc = 1.f + ctxv[t];
        float sh = ctxv[64 + t];
        AB[t]      = inv * gm * sc;
        AB[64 + t] = (bt - mean * inv * gm) * sc + sh;
    }
}

__global__ __launch_bounds__(256) void k_norm(float* __restrict__ out,
                                              const float* __restrict__ AB) {
    __shared__ float4 lA[16], lB[16];
    int t = threadIdx.x;
    if (t < 16) {
        lA[t] = ((const float4*)AB)[t];
        lB[t] = ((const float4*)AB)[16 + t];
    }
    __syncthreads();
    const long total4 = (long)N_OUT * C_OUT / 4;
    long stride = (long)gridDim.x * 256;
    for (long i = (long)blockIdx.x * 256 + t; i < total4; i += stride) {
        float4 v = ((float4*)out)[i];
        float4 a = lA[i & 15], b = lB[i & 15];
        v.x = fmaxf(fmaf(v.x, a.x, b.x), 0.f);
        v.y = fmaxf(fmaf(v.y, a.y, b.y), 0.f);
        v.z = fmaxf(fmaf(v.z, a.z, b.z), 0.f);
        v.w = fmaxf(fmaf(v.w, a.w, b.w), 0.f);
        ((float4*)out)[i] = v;
    }
}

// ==================== tier-B (round-4 validated path) ====================

__global__ __launch_bounds__(256) void k_scat2(const int* __restrict__ out_idx,
                                               const int* __restrict__ offs,
                                               const float* __restrict__ w,
                                               int* __restrict__ cnt,
                                               int* __restrict__ rlist,
                                               ushort* __restrict__ whl) {
    int b = blockIdx.x;
    if (b < PT_BLOCKS) {
        int i = b * 256 + threadIdx.x;
        if (i < N_IN) {
            int o = out_idx[i];
            int pos = atomicAdd(&cnt[o], 1);
            if (pos < CAP) rlist[o * CAP + pos] = i | (offs[i] << 21);
        }
    } else {
        int e = (b - PT_BLOCKS) * 256 + threadIdx.x;
        int c = e >> 11, t = (e >> 9) & 3, l = (e >> 3) & 63, kp = e & 7;
        int j = 4 * c + (l >> 4);
        int n = t * 16 + (l & 15);
        float v = w[kp * 2048 + j * 64 + n];
        unsigned bits = __float_as_uint(v);
        float lo = v - __uint_as_float(bits & 0xFFFF0000u);
        whl[e]         = (ushort)(bits >> 16);
        whl[16384 + e] = (ushort)(__float_as_uint(lo) >> 16);
    }
}

__global__ __launch_bounds__(128) void k_gconv3(const float* __restrict__ xf,
                                                const int* __restrict__ cnt,
                                                const int* __restrict__ rlist,
                                                const ushort* __restrict__ whl,
                                                float* __restrict__ out) {
    __shared__ float vxl[2 * 4640];
    int lane = threadIdx.x & 63;
    int wv = threadIdx.x >> 6;
    int g = blockIdx.x * 2 + wv;
    int base = g * 16;
    if (base >= N_OUT) return;
    float* VX = vxl + wv * 4640;

    float4* z4 = (float4*)VX;
    float4 zz = make_float4(0.f, 0.f, 0.f, 0.f);
#pragma unroll
    for (int i = 0; i < 19; ++i) {
        int p = i * 64 + lane;
        if (p < 1156) z4[p] = zz;
    }

    int slot = lane >> 3, jq = lane & 7;
    int cv = cnt[base + (lane & 15)];
    const int* rbase = rlist + (size_t)base * CAP;
    int pkA = rbase[slot * CAP + jq];
    int pkB = rbase[(8 + slot) * CAP + jq];
    int pkC = rbase[slot * CAP + 8 + jq];
    int pkD = rbase[(8 + slot) * CAP + 8 + jq];

#pragma unroll
    for (int r = 0; r < 16; ++r) {
        int cr = __builtin_amdgcn_readlane(cv, r);
        if (cr > CAP) cr = CAP;
        if (cr == 0) continue;
        {
            int pk = __shfl(r < 8 ? pkA : pkB, (r & 7) * 8 + slot, 64);
            int idx = pk & 0x1FFFFF; if (idx > N_IN - 1) idx = N_IN - 1;
            int kp = (pk >> 21) & 7;
            const float4 x = *(const float4*)(xf + (size_t)idx * 32 + jq * 4);
            float* dst = VX + r * 289 + 36 * jq + kp;
            if (slot < cr) {
                atomicAdd(dst + 0,  x.x);
                atomicAdd(dst + 9,  x.y);
                atomicAdd(dst + 18, x.z);
                atomicAdd(dst + 27, x.w);
            }
        }
        if (cr > 8) {
            int pk = __shfl(r < 8 ? pkC : pkD, (r & 7) * 8 + slot, 64);
            int idx = pk & 0x1FFFFF; if (idx > N_IN - 1) idx = N_IN - 1;
            int kp = (pk >> 21) & 7;
            const float4 x = *(const float4*)(xf + (size_t)idx * 32 + jq * 4);
            float* dst = VX + r * 289 + 36 * jq + kp;
            if (8 + slot < cr) {
                atomicAdd(dst + 0,  x.x);
                atomicAdd(dst + 9,  x.y);
                atomicAdd(dst + 18, x.z);
                atomicAdd(dst + 27, x.w);
            }
        }
        if (cr > 16) {
            for (int p0 = 16; p0 < cr; p0 += 8) {
                int pp = p0 + slot; if (pp > cr - 1) pp = cr - 1;
                int pk = rlist[((size_t)base + r) * CAP + pp];
                int idx = pk & 0x1FFFFF; if (idx > N_IN - 1) idx = N_IN - 1;
                int kp = (pk >> 21) & 7;
                const float4 x = *(const float4*)(xf + (size_t)idx * 32 + jq * 4);
                float* dst = VX + r * 289 + 36 * jq + kp;
                if (p0 + slot < cr) {
                    atomicAdd(dst + 0,  x.x);
                    atomicAdd(dst + 9,  x.y);
                    atomicAdd(dst + 18, x.z);
                    atomicAdd(dst + 27, x.w);
                }
            }
        }
    }

    __builtin_amdgcn_sched_barrier(0);
    asm volatile("s_waitcnt lgkmcnt(0)" ::: "memory");
    __builtin_amdgcn_sched_barrier(0);

    int o = lane >> 4;
    int n16 = lane & 15;
    f32x4 zacc = {0.f, 0.f, 0.f, 0.f};
    f32x4 acc0 = zacc, acc1 = zacc, acc2 = zacc, acc3 = zacc;
    const short8* wh = (const short8*)whl;
    const short8* wl = wh + 2048;

#pragma unroll
    for (int c = 0; c < 8; ++c) {
        const float* src = VX + n16 * 289 + (4 * c + o) * 9;
        float a[8];
#pragma unroll
        for (int el = 0; el < 8; ++el) a[el] = src[el];
        short8 ahi, alo;
#pragma unroll
        for (int el = 0; el < 8; ++el) {
            unsigned b = __float_as_uint(a[el]);
            ahi[el] = (short)(b >> 16);
            float lo = a[el] - __uint_as_float(b & 0xFFFF0000u);
            alo[el] = (short)(__float_as_uint(lo) >> 16);
        }
#pragma unroll
        for (int t = 0; t < 4; ++t) {
            short8 bh = wh[(c * 4 + t) * 64 + lane];
            short8 bl = wl[(c * 4 + t) * 64 + lane];
            f32x4* pa = (t == 0) ? &acc0 : (t == 1) ? &acc1 : (t == 2) ? &acc2 : &acc3;
            *pa = __builtin_amdgcn_mfma_f32_16x16x32_bf16(ahi, bh, *pa, 0, 0, 0);
            *pa = __builtin_amdgcn_mfma_f32_16x16x32_bf16(alo, bh, *pa, 0, 0, 0);
            *pa = __builtin_amdgcn_mfma_f32_16x16x32_bf16(ahi, bl, *pa, 0, 0, 0);
        }
    }

#pragma unroll
    for (int t = 0; t < 4; ++t) {
        f32x4 a = (t == 0) ? acc0 : (t == 1) ? acc1 : (t == 2) ? acc2 : acc3;
#pragma unroll
        for (int reg = 0; reg < 4; ++reg)
            out[(size_t)(base + o * 4 + reg) * 64 + t * 16 + n16] = a[reg];
    }
}

// ============================== launch ==============================

extern "C" void kernel_launch(void* const* d_in, const int* in_sizes, int n_in,
                              void* d_out, int out_size, void* d_ws, size_t ws_size,
                              hipStream_t stream) {
    const float* in_feats = (const float*)d_in[0];
    const int*   offs     = (const int*)d_in[1];
    const int*   out_idx  = (const int*)d_in[2];
    const float* weight   = (const float*)d_in[3];
    const float* gamma    = (const float*)d_in[4];
    const float* beta     = (const float*)d_in[5];
    const float* context  = (const float*)d_in[6];
    const float* ctx_w    = (const float*)d_in[7];
    const int*   cond     = (const int*)d_in[8];
    float* out = (float*)d_out;

    int*   wsi = (int*)d_ws;
    float* wsf = (float*)d_ws;

    if (ws_size >= TA_NEED_BYTES) {
        // ---- tier-A: rank(+zero) -> scan_a -> scan_c2 -> scatidx(+wpack) -> gconv13 ----
        int*    S      = wsi;                     // wsi[r] = start of row r
        ushort* whl    = (ushort*)(wsf + TA_WHL);
        int*    bsum   = wsi + TA_BSUM;
        float*  smalls = wsf + TA_SMALL;          // sums[64], sumsq[64], AB[128]
        int*    cnt    = wsi + TA_CNT;
        int*    idxg   = wsi + TA_IDXG;
        int*    pos0   = wsi + TA_POS;

        hipMemsetAsync(cnt, 0, (size_t)N_SCAN * 4, stream);

        k_rank<<<PT_BLOCKS + 1, 256, 0, stream>>>(out_idx, cnt, pos0, smalls);
        k_scan_a<<<N_SBLK, 256, 0, stream>>>(cnt, S, bsum);
        k_scan_c2<<<N_SBLK, 256, 0, stream>>>(S, bsum);
        k_scatidx<<<PT_BLOCKS + 64, 256, 0, stream>>>(out_idx, offs, pos0, S,
                                                      weight, idxg, whl);
        k_gconv13<<<31250, 64, 0, stream>>>(in_feats, idxg, wsi, whl, out);

        k_stats<<<2048, 256, 0, stream>>>(out, smalls, smalls + 64);
        k_ctxprep<<<1, 256, 0, stream>>>(context, ctx_w, smalls, smalls + 64,
                                         gamma, beta, cond, smalls + 128);
        k_norm<<<2048, 256, 0, stream>>>(out, smalls + 128);
    } else {
        // -------- tier-B: round-4 validated path --------
        int*    cnt    = wsi;
        ushort* whl    = (ushort*)(wsf + T1_WT);
        float*  smalls = wsf + T1_SMALL;
        int*    rlist  = wsi + T1_RLIST;

        hipMemsetAsync(cnt, 0, (size_t)N_OUT * 4, stream);
        hipMemsetAsync(smalls, 0, 128 * 4, stream);

        k_scat2<<<PT_BLOCKS + 64, 256, 0, stream>>>(out_idx, offs, weight, cnt, rlist, whl);
        k_gconv3<<<7813, 128, 0, stream>>>(in_feats, cnt, rlist, whl, out);

        k_stats<<<2048, 256, 0, stream>>>(out, smalls, smalls + 64);
        k_ctxprep<<<1, 256, 0, stream>>>(context, ctx_w, smalls, smalls + 64,
                                         gamma, beta, cond, smalls + 128);
        k_norm<<<2048, 256, 0, stream>>>(out, smalls + 128);
    }
}

// Round 22
// 408.776 us; speedup vs baseline: 1.0056x; 1.0056x over previous
//
#include <hip/hip_runtime.h>

#define N_IN 2000000
#define N_OUT 250000
#define C_IN 32
#define C_OUT 64
#define K_VOL 8
#define EPS 1e-5f
#define CAP 32

#define PT_BLOCKS 7813         // ceil(N_IN/256)
#define N_SCAN 250112          // 977*256
#define N_SBLK 977

typedef __attribute__((ext_vector_type(8))) short short8;
typedef __attribute__((ext_vector_type(4))) float f32x4;

// ======== tier-A workspace layout (int units) ========
#define TA_WHL    250368
#define TA_BSUM   266752
#define TA_SMALL  267776
#define TA_CNT    268288
#define TA_IDXG   1018400                                          // idxg[2M]
#define TA_POS    (TA_IDXG + N_IN)                                 // pos0[2M]
#define TA_NEED_BYTES ((size_t)(TA_POS + N_IN) * 4)                // ~20 MB

// ======== tier-B (round-4 validated) workspace layout ========
#define T1_WT     250000
#define T1_SMALL  266384
#define T1_RLIST  266768
#define T1_NEED_BYTES ((size_t)(T1_RLIST + N_OUT * CAP) * 4)

// ==================== tier-A: single-atomic-pass counting sort ====================
// +1 tail block zeroes smalls[128] (consumed much later by k_stats/k_ctxprep).
__global__ __launch_bounds__(256) void k_rank(const int* __restrict__ out_idx,
                                              int* __restrict__ cnt,
                                              int* __restrict__ pos0,
                                              float* __restrict__ smalls) {
    int b = blockIdx.x;
    if (b < PT_BLOCKS) {
        int i = b * 256 + threadIdx.x;
        if (i < N_IN) pos0[i] = atomicAdd(&cnt[out_idx[i]], 1);
    } else {
        if (threadIdx.x < 128) smalls[threadIdx.x] = 0.f;
    }
}

__global__ __launch_bounds__(256) void k_scan_a(const int* __restrict__ cnt,
                                                int* __restrict__ S,
                                                int* __restrict__ bsum) {
    __shared__ int sh[256];
    int t = threadIdx.x;
    int g = blockIdx.x * 256 + t;
    int v = cnt[g];
    sh[t] = v;
    __syncthreads();
#pragma unroll
    for (int off = 1; off < 256; off <<= 1) {
        int a = (t >= off) ? sh[t - off] : 0;
        __syncthreads();
        sh[t] += a;
        __syncthreads();
    }
    S[g] = sh[t] - v;              // exclusive within block
    if (t == 255) bsum[blockIdx.x] = sh[255];
}

// scan_b folded in: each block sums bsum[j < blockIdx] (L2-hot) via tree-reduce.
__global__ __launch_bounds__(256) void k_scan_c2(int* __restrict__ S,
                                                 const int* __restrict__ bsum) {
    __shared__ int red[256];
    int t = threadIdx.x, bid = blockIdx.x;
    int acc = 0;
    for (int j = t; j < bid; j += 256) acc += bsum[j];
    red[t] = acc;
    __syncthreads();
#pragma unroll
    for (int off = 128; off > 0; off >>= 1) {
        if (t < off) red[t] += red[t + off];
        __syncthreads();
    }
    S[bid * 256 + t] += red[0];
}

// Index-only scatter (L2-absorbed 4B writes) + fused weight hi/lo pack tail.
__global__ __launch_bounds__(256) void k_scatidx(const int* __restrict__ out_idx,
                                                 const int* __restrict__ offs,
                                                 const int* __restrict__ pos0,
                                                 const int* __restrict__ S,
                                                 const float* __restrict__ w,
                                                 int* __restrict__ idxg,
                                                 ushort* __restrict__ whl) {
    int b = blockIdx.x;
    if (b < PT_BLOCKS) {
        int i = b * 256 + threadIdx.x;
        if (i >= N_IN) return;
        int o = out_idx[i];
        int tag = offs[i] | ((o & 31) << 3);
        idxg[S[o] + pos0[i]] = i | (tag << 21);
    } else {
        int e = (b - PT_BLOCKS) * 256 + threadIdx.x;   // 0..16383
        int c = e >> 11, t = (e >> 9) & 3, l = (e >> 3) & 63, kp = e & 7;
        int j = 4 * c + (l >> 4);
        int n = t * 16 + (l & 15);
        float v = w[kp * 2048 + j * 64 + n];
        unsigned bits = __float_as_uint(v);
        float lo = v - __uint_as_float(bits & 0xFFFF0000u);
        whl[e]         = (ushort)(bits >> 16);
        whl[16384 + e] = (ushort)(__float_as_uint(lo) >> 16);
    }
}

// ==================== tier-A: gconv12 (validated rounds 19-20, best) ====================
__global__ __launch_bounds__(256) void k_gconv12(const float* __restrict__ xf,
                                                 const int* __restrict__ idxg,
                                                 const int* __restrict__ Sarr,
                                                 const ushort* __restrict__ whl,
                                                 float* __restrict__ out) {
    __shared__ float vxl[4 * 3104];
    int lane = threadIdx.x & 63;
    int wv = threadIdx.x >> 6;
    int g = blockIdx.x * 4 + wv;
    int base = g * 8;
    if (base >= N_OUT) return;
    float* VX = vxl + wv * 3104;
    short* XT = (short*)VX;   // 2 staging buffers of 3104 shorts each (alias VX head)

    int s = Sarr[base];
    int e = Sarr[base + 8];
    int slot = lane >> 3, jq = lane & 7;

    int tgt4[4];
#pragma unroll
    for (int m = 0; m < 4; ++m) {
        int bin0 = m * 16 + (lane & 15);
        tgt4[m] = (((base + (bin0 >> 3)) & 31) << 3) | (bin0 & 7);
    }

    f32x4 acc1[4][2];
#pragma unroll
    for (int m = 0; m < 4; ++m)
#pragma unroll
        for (int n = 0; n < 2; ++n)
            acc1[m][n] = (f32x4){0.f, 0.f, 0.f, 0.f};

    auto LOADBLK = [&](int p0, float4* xvv, int* tvv) {
        int pk[4];
#pragma unroll
        for (int q = 0; q < 4; ++q) {
            int p = p0 + q * 8 + slot;
            int pc = p < e ? p : e - 1;
            pk[q] = idxg[pc];                       // coalesced 4B (broadcast in group)
        }
#pragma unroll
        for (int q = 0; q < 4; ++q) {
            int p = p0 + q * 8 + slot;
            int idx = pk[q] & 0x1FFFFF;
            tvv[q] = (pk[q] >> 21) & 0xFF;
            xvv[q] = *(const float4*)(xf + (size_t)idx * 32 + jq * 4);  // full 128B line/group
            if (p >= e) xvv[q] = make_float4(0.f, 0.f, 0.f, 0.f);       // pad adds 0
        }
    };
    auto STAGE = [&](int bb, const float4* xvv, const int* tvv) {
        short* Xh = XT + bb * 3104;
        short* Xl = Xh + 1536;
        unsigned char* TGb = (unsigned char*)(Xh + 3072);
#pragma unroll
        for (int q = 0; q < 4; ++q) {
            int wpos = ((q ^ (jq & 3)) << 3) + slot;   // XOR block swizzle
#pragma unroll
            for (int i = 0; i < 4; ++i) {
                float v = (i == 0) ? xvv[q].x : (i == 1) ? xvv[q].y
                         : (i == 2) ? xvv[q].z : xvv[q].w;
                unsigned b = __float_as_uint(v);
                float lo = v - __uint_as_float(b & 0xFFFF0000u);
                int ch = 4 * jq + i;
                Xh[ch * 48 + wpos] = (short)(b >> 16);
                Xl[ch * 48 + wpos] = (short)(__float_as_uint(lo) >> 16);
            }
            if (jq == 0) TGb[q * 8 + slot] = (unsigned char)tvv[q];
        }
    };

    if (e > s) {
        float4 xvA[4], xvB[4], xvC[4];
        int tvA[4], tvB[4], tvC[4];
        int nIt = (e - s + 31) >> 5;
        LOADBLK(s, xvA, tvA);                    // it 0
        LOADBLK(s + 32, xvB, tvB);               // it 1 (clamped if absent)
        STAGE(0, xvA, tvA);
        for (int it = 0; it < nIt; ++it) {
            int cur = it & 1;
            if (it + 2 < nIt) LOADBLK(s + (it + 2) * 32, xvC, tvC);  // 2-deep prefetch

            asm volatile("s_waitcnt lgkmcnt(0)" ::: "memory");  // stage(cur) drained

            const short* Xh = XT + cur * 3104;
            const short* Xl = Xh + 1536;
            const unsigned char* TGb = (const unsigned char*)(Xh + 3072);
            unsigned long long t8 = *(const unsigned long long*)(TGb + 8 * (lane >> 4));
            int tgv[8];
#pragma unroll
            for (int e2 = 0; e2 < 8; ++e2) tgv[e2] = (int)((t8 >> (8 * e2)) & 0xFF);
            short8 bhf[2], blf[2];
#pragma unroll
            for (int n = 0; n < 2; ++n) {
                int ch = n * 16 + (lane & 15);
                int off = ch * 48 + 8 * ((lane >> 4) ^ ((ch >> 2) & 3));
                bhf[n] = *(const short8*)(Xh + off);
                blf[n] = *(const short8*)(Xl + off);
            }

            // ---- issue next-buffer STAGE writes BEFORE MFMA (overlap) ----
            if (it + 1 < nIt) STAGE(cur ^ 1, xvB, tvB);
            __builtin_amdgcn_sched_barrier(0);   // pin: writes issue before MFMA

#pragma unroll
            for (int m = 0; m < 4; ++m) {
                short8 ah;
#pragma unroll
                for (int e2 = 0; e2 < 8; ++e2)
                    ah[e2] = (tgv[e2] == tgt4[m]) ? (short)0x3F80 : (short)0;
#pragma unroll
                for (int n = 0; n < 2; ++n) {
                    acc1[m][n] = __builtin_amdgcn_mfma_f32_16x16x32_bf16(ah, bhf[n], acc1[m][n], 0, 0, 0);
                    acc1[m][n] = __builtin_amdgcn_mfma_f32_16x16x32_bf16(ah, blf[n], acc1[m][n], 0, 0, 0);
                }
            }

            if (it + 1 < nIt) {
#pragma unroll
                for (int q = 0; q < 4; ++q) { xvB[q] = xvC[q]; tvB[q] = tvC[q]; }
            }
        }
    }

    asm volatile("s_waitcnt lgkmcnt(0)" ::: "memory");

    // ---- deposit XS -> VX[r*289 + ch*9 + kp] (r in 0..7, full coverage) ----
#pragma unroll
    for (int m = 0; m < 4; ++m)
#pragma unroll
        for (int n = 0; n < 2; ++n)
#pragma unroll
            for (int reg = 0; reg < 4; ++reg) {
                int bin = m * 16 + (lane >> 4) * 4 + reg;     // 0..63
                VX[(bin >> 3) * 289 + (n * 16 + (lane & 15)) * 9 + (bin & 7)] = acc1[m][n][reg];
            }

    __builtin_amdgcn_sched_barrier(0);
    asm volatile("s_waitcnt lgkmcnt(0)" ::: "memory");
    __builtin_amdgcn_sched_barrier(0);

    // ---- GEMM-2: out[8x64] = XS[8x256] @ W[256x64], split-bf16, M padded to 16 ----
    int o = lane >> 4;
    int n16 = lane & 15;
    f32x4 zacc = {0.f, 0.f, 0.f, 0.f};
    f32x4 acc0 = zacc, accA = zacc, accB = zacc, accC = zacc;
    const short8* wh = (const short8*)whl;
    const short8* wl = wh + 2048;

#pragma unroll
    for (int c = 0; c < 8; ++c) {
        float a[8];
        if (n16 < 8) {
            const float* src = VX + n16 * 289 + (4 * c + o) * 9;
#pragma unroll
            for (int el = 0; el < 8; ++el) a[el] = src[el];
        } else {
#pragma unroll
            for (int el = 0; el < 8; ++el) a[el] = 0.f;
        }
        short8 ahi, alo;
#pragma unroll
        for (int el = 0; el < 8; ++el) {
            unsigned b = __float_as_uint(a[el]);
            ahi[el] = (short)(b >> 16);
            float lo = a[el] - __uint_as_float(b & 0xFFFF0000u);
            alo[el] = (short)(__float_as_uint(lo) >> 16);
        }
#pragma unroll
        for (int t = 0; t < 4; ++t) {
            short8 bh = wh[(c * 4 + t) * 64 + lane];
            short8 bl = wl[(c * 4 + t) * 64 + lane];
            f32x4* pa = (t == 0) ? &acc0 : (t == 1) ? &accA : (t == 2) ? &accB : &accC;
            *pa = __builtin_amdgcn_mfma_f32_16x16x32_bf16(ahi, bh, *pa, 0, 0, 0);
            *pa = __builtin_amdgcn_mfma_f32_16x16x32_bf16(alo, bh, *pa, 0, 0, 0);
            *pa = __builtin_amdgcn_mfma_f32_16x16x32_bf16(ahi, bl, *pa, 0, 0, 0);
        }
    }

    if (o < 2) {                                   // D rows 0..7 only
#pragma unroll
        for (int t = 0; t < 4; ++t) {
            f32x4 a = (t == 0) ? acc0 : (t == 1) ? accA : (t == 2) ? accB : accC;
#pragma unroll
            for (int reg = 0; reg < 4; ++reg)
                out[(size_t)(base + o * 4 + reg) * 64 + t * 16 + n16] = a[reg];
        }
    }
}

// ==================== shared post-passes ====================

__global__ __launch_bounds__(256) void k_stats(const float* __restrict__ out,
                                               float* __restrict__ sums,
                                               float* __restrict__ sumsq) {
    int t = threadIdx.x;
    long stride = (long)gridDim.x * 256;
    float s = 0.f, q = 0.f;
    for (long i = (long)blockIdx.x * 256 + t; i < (long)N_OUT * C_OUT; i += stride) {
        float v = out[i];
        s += v;
        q = fmaf(v, v, q);
    }
    __shared__ float ls[256], lq[256];
    ls[t] = s; lq[t] = q;
    __syncthreads();
    if (t < 64) {
        s = ls[t] + ls[t + 64] + ls[t + 128] + ls[t + 192];
        q = lq[t] + lq[t + 64] + lq[t + 128] + lq[t + 192];
        atomicAdd(&sums[t], s);
        atomicAdd(&sumsq[t], q);
    }
}

__global__ __launch_bounds__(256) void k_ctxprep(const float* __restrict__ context,
                                                 const float* __restrict__ ctx_w,
                                                 const float* __restrict__ sums,
                                                 const float* __restrict__ sumsq,
                                                 const float* __restrict__ gamma,
                                                 const float* __restrict__ beta,
                                                 const int* __restrict__ cond,
                                                 float* __restrict__ AB) {
    __shared__ float part[256];
    __shared__ float ctxv[128];
    int t = threadIdx.x;
    int col = t & 127, half = t >> 7;
    float s = 0.f;
    for (int r = half * 128; r < half * 128 + 128; ++r)
        s = fmaf(context[r], ctx_w[r * 128 + col], s);
    part[t] = s;
    __syncthreads();
    if (t < 128) ctxv[t] = part[t] + part[t + 128];
    __syncthreads();
    if (t < 64) {
        float mean = sums[t] * (1.f / N_OUT);
        float var  = sumsq[t] * (1.f / N_OUT) - mean * mean;
        float inv  = rsqrtf(var + EPS);
        int cd = cond[0];
        float gm = gamma[cd * C_OUT + t], bt = beta[cd * C_OUT + t];
        float sc = 1.f + ctxv[t];
        float sh = ctxv[64 + t];
        AB[t]      = inv * gm * sc;
        AB[64 + t] = (bt - mean * inv * gm) * sc + sh;
    }
}

__global__ __launch_bounds__(256) void k_norm(float* __restrict__ out,
                                              const float* __restrict__ AB) {
    __shared__ float4 lA[16], lB[16];
    int t = threadIdx.x;
    if (t < 16) {
        lA[t] = ((const float4*)AB)[t];
        lB[t] = ((const float4*)AB)[16 + t];
    }
    __syncthreads();
    const long total4 = (long)N_OUT * C_OUT / 4;
    long stride = (long)gridDim.x * 256;
    for (long i = (long)blockIdx.x * 256 + t; i < total4; i += stride) {
        float4 v = ((float4*)out)[i];
        float4 a = lA[i & 15], b = lB[i & 15];
        v.x = fmaxf(fmaf(v.x, a.x, b.x), 0.f);
        v.y = fmaxf(fmaf(v.y, a.y, b.y), 0.f);
        v.z = fmaxf(fmaf(v.z, a.z, b.z), 0.f);
        v.w = fmaxf(fmaf(v.w, a.w, b.w), 0.f);
        ((float4*)out)[i] = v;
    }
}

// ==================== tier-B (round-4 validated path) ====================

__global__ __launch_bounds__(256) void k_scat2(const int* __restrict__ out_idx,
                                               const int* __restrict__ offs,
                                               const float* __restrict__ w,
                                               int* __restrict__ cnt,
                                               int* __restrict__ rlist,
                                               ushort* __restrict__ whl) {
    int b = blockIdx.x;
    if (b < PT_BLOCKS) {
        int i = b * 256 + threadIdx.x;
        if (i < N_IN) {
            int o = out_idx[i];
            int pos = atomicAdd(&cnt[o], 1);
            if (pos < CAP) rlist[o * CAP + pos] = i | (offs[i] << 21);
        }
    } else {
        int e = (b - PT_BLOCKS) * 256 + threadIdx.x;
        int c = e >> 11, t = (e >> 9) & 3, l = (e >> 3) & 63, kp = e & 7;
        int j = 4 * c + (l >> 4);
        int n = t * 16 + (l & 15);
        float v = w[kp * 2048 + j * 64 + n];
        unsigned bits = __float_as_uint(v);
        float lo = v - __uint_as_float(bits & 0xFFFF0000u);
        whl[e]         = (ushort)(bits >> 16);
        whl[16384 + e] = (ushort)(__float_as_uint(lo) >> 16);
    }
}

__global__ __launch_bounds__(128) void k_gconv3(const float* __restrict__ xf,
                                                const int* __restrict__ cnt,
                                                const int* __restrict__ rlist,
                                                const ushort* __restrict__ whl,
                                                float* __restrict__ out) {
    __shared__ float vxl[2 * 4640];
    int lane = threadIdx.x & 63;
    int wv = threadIdx.x >> 6;
    int g = blockIdx.x * 2 + wv;
    int base = g * 16;
    if (base >= N_OUT) return;
    float* VX = vxl + wv * 4640;

    float4* z4 = (float4*)VX;
    float4 zz = make_float4(0.f, 0.f, 0.f, 0.f);
#pragma unroll
    for (int i = 0; i < 19; ++i) {
        int p = i * 64 + lane;
        if (p < 1156) z4[p] = zz;
    }

    int slot = lane >> 3, jq = lane & 7;
    int cv = cnt[base + (lane & 15)];
    const int* rbase = rlist + (size_t)base * CAP;
    int pkA = rbase[slot * CAP + jq];
    int pkB = rbase[(8 + slot) * CAP + jq];
    int pkC = rbase[slot * CAP + 8 + jq];
    int pkD = rbase[(8 + slot) * CAP + 8 + jq];

#pragma unroll
    for (int r = 0; r < 16; ++r) {
        int cr = __builtin_amdgcn_readlane(cv, r);
        if (cr > CAP) cr = CAP;
        if (cr == 0) continue;
        {
            int pk = __shfl(r < 8 ? pkA : pkB, (r & 7) * 8 + slot, 64);
            int idx = pk & 0x1FFFFF; if (idx > N_IN - 1) idx = N_IN - 1;
            int kp = (pk >> 21) & 7;
            const float4 x = *(const float4*)(xf + (size_t)idx * 32 + jq * 4);
            float* dst = VX + r * 289 + 36 * jq + kp;
            if (slot < cr) {
                atomicAdd(dst + 0,  x.x);
                atomicAdd(dst + 9,  x.y);
                atomicAdd(dst + 18, x.z);
                atomicAdd(dst + 27, x.w);
            }
        }
        if (cr > 8) {
            int pk = __shfl(r < 8 ? pkC : pkD, (r & 7) * 8 + slot, 64);
            int idx = pk & 0x1FFFFF; if (idx > N_IN - 1) idx = N_IN - 1;
            int kp = (pk >> 21) & 7;
            const float4 x = *(const float4*)(xf + (size_t)idx * 32 + jq * 4);
            float* dst = VX + r * 289 + 36 * jq + kp;
            if (8 + slot < cr) {
                atomicAdd(dst + 0,  x.x);
                atomicAdd(dst + 9,  x.y);
                atomicAdd(dst + 18, x.z);
                atomicAdd(dst + 27, x.w);
            }
        }
        if (cr > 16) {
            for (int p0 = 16; p0 < cr; p0 += 8) {
                int pp = p0 + slot; if (pp > cr - 1) pp = cr - 1;
                int pk = rlist[((size_t)base + r) * CAP + pp];
                int idx = pk & 0x1FFFFF; if (idx > N_IN - 1) idx = N_IN - 1;
                int kp = (pk >> 21) & 7;
                const float4 x = *(const float4*)(xf + (size_t)idx * 32 + jq * 4);
                float* dst = VX + r * 289 + 36 * jq + kp;
                if (p0 + slot < cr) {
                    atomicAdd(dst + 0,  x.x);
                    atomicAdd(dst + 9,  x.y);
                    atomicAdd(dst + 18, x.z);
                    atomicAdd(dst + 27, x.w);
                }
            }
        }
    }

    __builtin_amdgcn_sched_barrier(0);
    asm volatile("s_waitcnt lgkmcnt(0)" ::: "memory");
    __builtin_amdgcn_sched_barrier(0);

    int o = lane >> 4;
    int n16 = lane & 15;
    f32x4 zacc = {0.f, 0.f, 0.f, 0.f};
    f32x4 acc0 = zacc, acc1 = zacc, acc2 = zacc, acc3 = zacc;
    const short8* wh = (const short8*)whl;
    const short8* wl = wh + 2048;

#pragma unroll
    for (int c = 0; c < 8; ++c) {
        const float* src = VX + n16 * 289 + (4 * c + o) * 9;
        float a[8];
#pragma unroll
        for (int el = 0; el < 8; ++el) a[el] = src[el];
        short8 ahi, alo;
#pragma unroll
        for (int el = 0; el < 8; ++el) {
            unsigned b = __float_as_uint(a[el]);
            ahi[el] = (short)(b >> 16);
            float lo = a[el] - __uint_as_float(b & 0xFFFF0000u);
            alo[el] = (short)(__float_as_uint(lo) >> 16);
        }
#pragma unroll
        for (int t = 0; t < 4; ++t) {
            short8 bh = wh[(c * 4 + t) * 64 + lane];
            short8 bl = wl[(c * 4 + t) * 64 + lane];
            f32x4* pa = (t == 0) ? &acc0 : (t == 1) ? &acc1 : (t == 2) ? &acc2 : &acc3;
            *pa = __builtin_amdgcn_mfma_f32_16x16x32_bf16(ahi, bh, *pa, 0, 0, 0);
            *pa = __builtin_amdgcn_mfma_f32_16x16x32_bf16(alo, bh, *pa, 0, 0, 0);
            *pa = __builtin_amdgcn_mfma_f32_16x16x32_bf16(ahi, bl, *pa, 0, 0, 0);
        }
    }

#pragma unroll
    for (int t = 0; t < 4; ++t) {
        f32x4 a = (t == 0) ? acc0 : (t == 1) ? acc1 : (t == 2) ? acc2 : acc3;
#pragma unroll
        for (int reg = 0; reg < 4; ++reg)
            out[(size_t)(base + o * 4 + reg) * 64 + t * 16 + n16] = a[reg];
    }
}

// ============================== launch ==============================

extern "C" void kernel_launch(void* const* d_in, const int* in_sizes, int n_in,
                              void* d_out, int out_size, void* d_ws, size_t ws_size,
                              hipStream_t stream) {
    const float* in_feats = (const float*)d_in[0];
    const int*   offs     = (const int*)d_in[1];
    const int*   out_idx  = (const int*)d_in[2];
    const float* weight   = (const float*)d_in[3];
    const float* gamma    = (const float*)d_in[4];
    const float* beta     = (const float*)d_in[5];
    const float* context  = (const float*)d_in[6];
    const float* ctx_w    = (const float*)d_in[7];
    const int*   cond     = (const int*)d_in[8];
    float* out = (float*)d_out;

    int*   wsi = (int*)d_ws;
    float* wsf = (float*)d_ws;

    if (ws_size >= TA_NEED_BYTES) {
        // ---- tier-A (round-20 best): rank(+zero) -> scan_a -> scan_c2 ->
        //      scatidx(+wpack) -> gconv12 -> stats -> ctxprep -> norm ----
        int*    S      = wsi;                     // wsi[r] = start of row r
        ushort* whl    = (ushort*)(wsf + TA_WHL);
        int*    bsum   = wsi + TA_BSUM;
        float*  smalls = wsf + TA_SMALL;          // sums[64], sumsq[64], AB[128]
        int*    cnt    = wsi + TA_CNT;
        int*    idxg   = wsi + TA_IDXG;
        int*    pos0   = wsi + TA_POS;

        hipMemsetAsync(cnt, 0, (size_t)N_SCAN * 4, stream);

        k_rank<<<PT_BLOCKS + 1, 256, 0, stream>>>(out_idx, cnt, pos0, smalls);
        k_scan_a<<<N_SBLK, 256, 0, stream>>>(cnt, S, bsum);
        k_scan_c2<<<N_SBLK, 256, 0, stream>>>(S, bsum);
        k_scatidx<<<PT_BLOCKS + 64, 256, 0, stream>>>(out_idx, offs, pos0, S,
                                                      weight, idxg, whl);
        k_gconv12<<<7813, 256, 0, stream>>>(in_feats, idxg, wsi, whl, out);

        k_stats<<<2048, 256, 0, stream>>>(out, smalls, smalls + 64);
        k_ctxprep<<<1, 256, 0, stream>>>(context, ctx_w, smalls, smalls + 64,
                                         gamma, beta, cond, smalls + 128);
        k_norm<<<2048, 256, 0, stream>>>(out, smalls + 128);
    } else {
        // -------- tier-B: round-4 validated path --------
        int*    cnt    = wsi;
        ushort* whl    = (ushort*)(wsf + T1_WT);
        float*  smalls = wsf + T1_SMALL;
        int*    rlist  = wsi + T1_RLIST;

        hipMemsetAsync(cnt, 0, (size_t)N_OUT * 4, stream);
        hipMemsetAsync(smalls, 0, 128 * 4, stream);

        k_scat2<<<PT_BLOCKS + 64, 256, 0, stream>>>(out_idx, offs, weight, cnt, rlist, whl);
        k_gconv3<<<7813, 128, 0, stream>>>(in_feats, cnt, rlist, whl, out);

        k_stats<<<2048, 256, 0, stream>>>(out, smalls, smalls + 64);
        k_ctxprep<<<1, 256, 0, stream>>>(context, ctx_w, smalls, smalls + 64,
                                         gamma, beta, cond, smalls + 128);
        k_norm<<<2048, 256, 0, stream>>>(out, smalls + 128);
    }
}

// Round 23
// 405.478 us; speedup vs baseline: 1.0137x; 1.0081x over previous
//
#include <hip/hip_runtime.h>

#define N_IN 2000000
#define N_OUT 250000
#define C_IN 32
#define C_OUT 64
#define K_VOL 8
#define EPS 1e-5f
#define CAP 32

#define PT_BLOCKS 7813         // ceil(N_IN/256)
#define N_SCAN 250112          // 977*256
#define N_SBLK 977
#define NWAVE 31252            // 7813*4 (conv waves; valid groups < 31250)

typedef __attribute__((ext_vector_type(8))) short short8;
typedef __attribute__((ext_vector_type(4))) float f32x4;

// ======== tier-A workspace layout (int units) ========
#define TA_WHL    250368
#define TA_BSUM   266752
#define TA_SMALL  267776
#define TA_CNT    268288
#define TA_IDXG   1018400                                          // idxg[2M]
#define TA_POS    (TA_IDXG + N_IN)                                 // pos0[2M]
#define TA_PART   (TA_POS + N_IN)                                  // part[128][31252]
#define TA_NEED_BYTES ((size_t)(TA_PART + 128 * NWAVE) * 4)        // ~36 MB

// ======== tier-B (round-4 validated) workspace layout ========
#define T1_WT     250000
#define T1_SMALL  266384
#define T1_RLIST  266768
#define T1_NEED_BYTES ((size_t)(T1_RLIST + N_OUT * CAP) * 4)

// ==================== tier-A: single-atomic-pass counting sort ====================

__global__ __launch_bounds__(256) void k_rank(const int* __restrict__ out_idx,
                                              int* __restrict__ cnt,
                                              int* __restrict__ pos0) {
    int i = blockIdx.x * 256 + threadIdx.x;
    if (i < N_IN) pos0[i] = atomicAdd(&cnt[out_idx[i]], 1);
}

__global__ __launch_bounds__(256) void k_scan_a(const int* __restrict__ cnt,
                                                int* __restrict__ S,
                                                int* __restrict__ bsum) {
    __shared__ int sh[256];
    int t = threadIdx.x;
    int g = blockIdx.x * 256 + t;
    int v = cnt[g];
    sh[t] = v;
    __syncthreads();
#pragma unroll
    for (int off = 1; off < 256; off <<= 1) {
        int a = (t >= off) ? sh[t - off] : 0;
        __syncthreads();
        sh[t] += a;
        __syncthreads();
    }
    S[g] = sh[t] - v;              // exclusive within block
    if (t == 255) bsum[blockIdx.x] = sh[255];
}

// scan_b folded in: each block sums bsum[j < blockIdx] (L2-hot) via tree-reduce.
__global__ __launch_bounds__(256) void k_scan_c2(int* __restrict__ S,
                                                 const int* __restrict__ bsum) {
    __shared__ int red[256];
    int t = threadIdx.x, bid = blockIdx.x;
    int acc = 0;
    for (int j = t; j < bid; j += 256) acc += bsum[j];
    red[t] = acc;
    __syncthreads();
#pragma unroll
    for (int off = 128; off > 0; off >>= 1) {
        if (t < off) red[t] += red[t + off];
        __syncthreads();
    }
    S[bid * 256 + t] += red[0];
}

// Index-only scatter (L2-absorbed 4B writes) + fused weight hi/lo pack tail.
__global__ __launch_bounds__(256) void k_scatidx(const int* __restrict__ out_idx,
                                                 const int* __restrict__ offs,
                                                 const int* __restrict__ pos0,
                                                 const int* __restrict__ S,
                                                 const float* __restrict__ w,
                                                 int* __restrict__ idxg,
                                                 ushort* __restrict__ whl) {
    int b = blockIdx.x;
    if (b < PT_BLOCKS) {
        int i = b * 256 + threadIdx.x;
        if (i >= N_IN) return;
        int o = out_idx[i];
        int tag = offs[i] | ((o & 31) << 3);
        idxg[S[o] + pos0[i]] = i | (tag << 21);
    } else {
        int e = (b - PT_BLOCKS) * 256 + threadIdx.x;   // 0..16383
        int c = e >> 11, t = (e >> 9) & 3, l = (e >> 3) & 63, kp = e & 7;
        int j = 4 * c + (l >> 4);
        int n = t * 16 + (l & 15);
        float v = w[kp * 2048 + j * 64 + n];
        unsigned bits = __float_as_uint(v);
        float lo = v - __uint_as_float(bits & 0xFFFF0000u);
        whl[e]         = (ushort)(bits >> 16);
        whl[16384 + e] = (ushort)(__float_as_uint(lo) >> 16);
    }
}

// ==================== tier-A: gconv12 + fused channel-stats epilogue ====================
// Hot loop byte-identical to validated gconv12; after GEMM-2 each wave reduces
// its 8x64 output to per-channel (s,q) partials and writes part[ch][g].
__global__ __launch_bounds__(256) void k_gconv14(const float* __restrict__ xf,
                                                 const int* __restrict__ idxg,
                                                 const int* __restrict__ Sarr,
                                                 const ushort* __restrict__ whl,
                                                 float* __restrict__ out,
                                                 float* __restrict__ part) {
    __shared__ float vxl[4 * 3104];
    int lane = threadIdx.x & 63;
    int wv = threadIdx.x >> 6;
    int g = blockIdx.x * 4 + wv;
    int base = g * 8;
    if (base >= N_OUT) return;
    float* VX = vxl + wv * 3104;
    short* XT = (short*)VX;   // 2 staging buffers of 3104 shorts each (alias VX head)

    int s = Sarr[base];
    int e = Sarr[base + 8];
    int slot = lane >> 3, jq = lane & 7;

    int tgt4[4];
#pragma unroll
    for (int m = 0; m < 4; ++m) {
        int bin0 = m * 16 + (lane & 15);
        tgt4[m] = (((base + (bin0 >> 3)) & 31) << 3) | (bin0 & 7);
    }

    f32x4 acc1[4][2];
#pragma unroll
    for (int m = 0; m < 4; ++m)
#pragma unroll
        for (int n = 0; n < 2; ++n)
            acc1[m][n] = (f32x4){0.f, 0.f, 0.f, 0.f};

    auto LOADBLK = [&](int p0, float4* xvv, int* tvv) {
        int pk[4];
#pragma unroll
        for (int q = 0; q < 4; ++q) {
            int p = p0 + q * 8 + slot;
            int pc = p < e ? p : e - 1;
            pk[q] = idxg[pc];                       // coalesced 4B (broadcast in group)
        }
#pragma unroll
        for (int q = 0; q < 4; ++q) {
            int p = p0 + q * 8 + slot;
            int idx = pk[q] & 0x1FFFFF;
            tvv[q] = (pk[q] >> 21) & 0xFF;
            xvv[q] = *(const float4*)(xf + (size_t)idx * 32 + jq * 4);  // full 128B line/group
            if (p >= e) xvv[q] = make_float4(0.f, 0.f, 0.f, 0.f);       // pad adds 0
        }
    };
    auto STAGE = [&](int bb, const float4* xvv, const int* tvv) {
        short* Xh = XT + bb * 3104;
        short* Xl = Xh + 1536;
        unsigned char* TGb = (unsigned char*)(Xh + 3072);
#pragma unroll
        for (int q = 0; q < 4; ++q) {
            int wpos = ((q ^ (jq & 3)) << 3) + slot;   // XOR block swizzle
#pragma unroll
            for (int i = 0; i < 4; ++i) {
                float v = (i == 0) ? xvv[q].x : (i == 1) ? xvv[q].y
                         : (i == 2) ? xvv[q].z : xvv[q].w;
                unsigned b = __float_as_uint(v);
                float lo = v - __uint_as_float(b & 0xFFFF0000u);
                int ch = 4 * jq + i;
                Xh[ch * 48 + wpos] = (short)(b >> 16);
                Xl[ch * 48 + wpos] = (short)(__float_as_uint(lo) >> 16);
            }
            if (jq == 0) TGb[q * 8 + slot] = (unsigned char)tvv[q];
        }
    };

    if (e > s) {
        float4 xvA[4], xvB[4], xvC[4];
        int tvA[4], tvB[4], tvC[4];
        int nIt = (e - s + 31) >> 5;
        LOADBLK(s, xvA, tvA);                    // it 0
        LOADBLK(s + 32, xvB, tvB);               // it 1 (clamped if absent)
        STAGE(0, xvA, tvA);
        for (int it = 0; it < nIt; ++it) {
            int cur = it & 1;
            if (it + 2 < nIt) LOADBLK(s + (it + 2) * 32, xvC, tvC);  // 2-deep prefetch

            asm volatile("s_waitcnt lgkmcnt(0)" ::: "memory");  // stage(cur) drained

            const short* Xh = XT + cur * 3104;
            const short* Xl = Xh + 1536;
            const unsigned char* TGb = (const unsigned char*)(Xh + 3072);
            unsigned long long t8 = *(const unsigned long long*)(TGb + 8 * (lane >> 4));
            int tgv[8];
#pragma unroll
            for (int e2 = 0; e2 < 8; ++e2) tgv[e2] = (int)((t8 >> (8 * e2)) & 0xFF);
            short8 bhf[2], blf[2];
#pragma unroll
            for (int n = 0; n < 2; ++n) {
                int ch = n * 16 + (lane & 15);
                int off = ch * 48 + 8 * ((lane >> 4) ^ ((ch >> 2) & 3));
                bhf[n] = *(const short8*)(Xh + off);
                blf[n] = *(const short8*)(Xl + off);
            }

            // ---- issue next-buffer STAGE writes BEFORE MFMA (overlap) ----
            if (it + 1 < nIt) STAGE(cur ^ 1, xvB, tvB);
            __builtin_amdgcn_sched_barrier(0);   // pin: writes issue before MFMA

#pragma unroll
            for (int m = 0; m < 4; ++m) {
                short8 ah;
#pragma unroll
                for (int e2 = 0; e2 < 8; ++e2)
                    ah[e2] = (tgv[e2] == tgt4[m]) ? (short)0x3F80 : (short)0;
#pragma unroll
                for (int n = 0; n < 2; ++n) {
                    acc1[m][n] = __builtin_amdgcn_mfma_f32_16x16x32_bf16(ah, bhf[n], acc1[m][n], 0, 0, 0);
                    acc1[m][n] = __builtin_amdgcn_mfma_f32_16x16x32_bf16(ah, blf[n], acc1[m][n], 0, 0, 0);
                }
            }

            if (it + 1 < nIt) {
#pragma unroll
                for (int q = 0; q < 4; ++q) { xvB[q] = xvC[q]; tvB[q] = tvC[q]; }
            }
        }
    }

    asm volatile("s_waitcnt lgkmcnt(0)" ::: "memory");

    // ---- deposit XS -> VX[r*289 + ch*9 + kp] (r in 0..7, full coverage) ----
#pragma unroll
    for (int m = 0; m < 4; ++m)
#pragma unroll
        for (int n = 0; n < 2; ++n)
#pragma unroll
            for (int reg = 0; reg < 4; ++reg) {
                int bin = m * 16 + (lane >> 4) * 4 + reg;     // 0..63
                VX[(bin >> 3) * 289 + (n * 16 + (lane & 15)) * 9 + (bin & 7)] = acc1[m][n][reg];
            }

    __builtin_amdgcn_sched_barrier(0);
    asm volatile("s_waitcnt lgkmcnt(0)" ::: "memory");
    __builtin_amdgcn_sched_barrier(0);

    // ---- GEMM-2: out[8x64] = XS[8x256] @ W[256x64], split-bf16, M padded to 16 ----
    int o = lane >> 4;
    int n16 = lane & 15;
    f32x4 zacc = {0.f, 0.f, 0.f, 0.f};
    f32x4 acc0 = zacc, accA = zacc, accB = zacc, accC = zacc;
    const short8* wh = (const short8*)whl;
    const short8* wl = wh + 2048;

#pragma unroll
    for (int c = 0; c < 8; ++c) {
        float a[8];
        if (n16 < 8) {
            const float* src = VX + n16 * 289 + (4 * c + o) * 9;
#pragma unroll
            for (int el = 0; el < 8; ++el) a[el] = src[el];
        } else {
#pragma unroll
            for (int el = 0; el < 8; ++el) a[el] = 0.f;
        }
        short8 ahi, alo;
#pragma unroll
        for (int el = 0; el < 8; ++el) {
            unsigned b = __float_as_uint(a[el]);
            ahi[el] = (short)(b >> 16);
            float lo = a[el] - __uint_as_float(b & 0xFFFF0000u);
            alo[el] = (short)(__float_as_uint(lo) >> 16);
        }
#pragma unroll
        for (int t = 0; t < 4; ++t) {
            short8 bh = wh[(c * 4 + t) * 64 + lane];
            short8 bl = wl[(c * 4 + t) * 64 + lane];
            f32x4* pa = (t == 0) ? &acc0 : (t == 1) ? &accA : (t == 2) ? &accB : &accC;
            *pa = __builtin_amdgcn_mfma_f32_16x16x32_bf16(ahi, bh, *pa, 0, 0, 0);
            *pa = __builtin_amdgcn_mfma_f32_16x16x32_bf16(alo, bh, *pa, 0, 0, 0);
            *pa = __builtin_amdgcn_mfma_f32_16x16x32_bf16(ahi, bl, *pa, 0, 0, 0);
        }
    }

    if (o < 2) {                                   // D rows 0..7 only
#pragma unroll
        for (int t = 0; t < 4; ++t) {
            f32x4 a = (t == 0) ? acc0 : (t == 1) ? accA : (t == 2) ? accB : accC;
#pragma unroll
            for (int reg = 0; reg < 4; ++reg)
                out[(size_t)(base + o * 4 + reg) * 64 + t * 16 + n16] = a[reg];
        }
    }

    // ---- fused channel stats: rows 8-15 are exactly 0 (padded A) ----
    float sv[4], qv[4];
#pragma unroll
    for (int t = 0; t < 4; ++t) {
        f32x4 a = (t == 0) ? acc0 : (t == 1) ? accA : (t == 2) ? accB : accC;
        float sa = 0.f, qa = 0.f;
#pragma unroll
        for (int reg = 0; reg < 4; ++reg) {
            sa += a[reg];
            qa = fmaf(a[reg], a[reg], qa);
        }
        sv[t] = sa; qv[t] = qa;
    }
#pragma unroll
    for (int t = 0; t < 4; ++t) {
        sv[t] += __shfl_xor(sv[t], 16, 64);
        sv[t] += __shfl_xor(sv[t], 32, 64);
        qv[t] += __shfl_xor(qv[t], 16, 64);
        qv[t] += __shfl_xor(qv[t], 32, 64);
    }
    if (lane < 16) {
#pragma unroll
        for (int t = 0; t < 4; ++t) {
            int ch = t * 16 + lane;
            part[(size_t)ch * NWAVE + g]        = sv[t];
            part[(size_t)(64 + ch) * NWAVE + g] = qv[t];
        }
    }
}

// ==================== tier-A: channel-major partial reduce (replaces k_stats) ====================
__global__ __launch_bounds__(256) void k_statsred(const float* __restrict__ part,
                                                  float* __restrict__ smalls) {
    __shared__ float red[256];
    int c = blockIdx.x;                 // 0..127 (0-63 sums, 64-127 sumsq)
    int t = threadIdx.x;
    const float* p = part + (size_t)c * NWAVE;
    float s = 0.f;
    for (int g = t; g < 31250; g += 256) s += p[g];
    red[t] = s;
    __syncthreads();
#pragma unroll
    for (int off = 128; off > 0; off >>= 1) {
        if (t < off) red[t] += red[t + off];
        __syncthreads();
    }
    if (t == 0) smalls[c] = red[0];
}

// ==================== shared post-passes ====================

__global__ __launch_bounds__(256) void k_stats(const float* __restrict__ out,
                                               float* __restrict__ sums,
                                               float* __restrict__ sumsq) {
    int t = threadIdx.x;
    long stride = (long)gridDim.x * 256;
    float s = 0.f, q = 0.f;
    for (long i = (long)blockIdx.x * 256 + t; i < (long)N_OUT * C_OUT; i += stride) {
        float v = out[i];
        s += v;
        q = fmaf(v, v, q);
    }
    __shared__ float ls[256], lq[256];
    ls[t] = s; lq[t] = q;
    __syncthreads();
    if (t < 64) {
        s = ls[t] + ls[t + 64] + ls[t + 128] + ls[t + 192];
        q = lq[t] + lq[t + 64] + lq[t + 128] + lq[t + 192];
        atomicAdd(&sums[t], s);
        atomicAdd(&sumsq[t], q);
    }
}

__global__ __launch_bounds__(256) void k_ctxprep(const float* __restrict__ context,
                                                 const float* __restrict__ ctx_w,
                                                 const float* __restrict__ sums,
                                                 const float* __restrict__ sumsq,
                                                 const float* __restrict__ gamma,
                                                 const float* __restrict__ beta,
                                                 const int* __restrict__ cond,
                                                 float* __restrict__ AB) {
    __shared__ float part[256];
    __shared__ float ctxv[128];
    int t = threadIdx.x;
    int col = t & 127, half = t >> 7;
    float s = 0.f;
    for (int r = half * 128; r < half * 128 + 128; ++r)
        s = fmaf(context[r], ctx_w[r * 128 + col], s);
    part[t] = s;
    __syncthreads();
    if (t < 128) ctxv[t] = part[t] + part[t + 128];
    __syncthreads();
    if (t < 64) {
        float mean = sums[t] * (1.f / N_OUT);
        float var  = sumsq[t] * (1.f / N_OUT) - mean * mean;
        float inv  = rsqrtf(var + EPS);
        int cd = cond[0];
        float gm = gamma[cd * C_OUT + t], bt = beta[cd * C_OUT + t];
        float sc = 1.f + ctxv[t];
        float sh = ctxv[64 + t];
        AB[t]      = inv * gm * sc;
        AB[64 + t] = (bt - mean * inv * gm) * sc + sh;
    }
}

__global__ __launch_bounds__(256) void k_norm(float* __restrict__ out,
                                              const float* __restrict__ AB) {
    __shared__ float4 lA[16], lB[16];
    int t = threadIdx.x;
    if (t < 16) {
        lA[t] = ((const float4*)AB)[t];
        lB[t] = ((const float4*)AB)[16 + t];
    }
    __syncthreads();
    const long total4 = (long)N_OUT * C_OUT / 4;
    long stride = (long)gridDim.x * 256;
    for (long i = (long)blockIdx.x * 256 + t; i < total4; i += stride) {
        float4 v = ((float4*)out)[i];
        float4 a = lA[i & 15], b = lB[i & 15];
        v.x = fmaxf(fmaf(v.x, a.x, b.x), 0.f);
        v.y = fmaxf(fmaf(v.y, a.y, b.y), 0.f);
        v.z = fmaxf(fmaf(v.z, a.z, b.z), 0.f);
        v.w = fmaxf(fmaf(v.w, a.w, b.w), 0.f);
        ((float4*)out)[i] = v;
    }
}

// ==================== tier-B (round-4 validated path) ====================

__global__ __launch_bounds__(256) void k_scat2(const int* __restrict__ out_idx,
                                               const int* __restrict__ offs,
                                               const float* __restrict__ w,
                                               int* __restrict__ cnt,
                                               int* __restrict__ rlist,
                                               ushort* __restrict__ whl) {
    int b = blockIdx.x;
    if (b < PT_BLOCKS) {
        int i = b * 256 + threadIdx.x;
        if (i < N_IN) {
            int o = out_idx[i];
            int pos = atomicAdd(&cnt[o], 1);
            if (pos < CAP) rlist[o * CAP + pos] = i | (offs[i] << 21);
        }
    } else {
        int e = (b - PT_BLOCKS) * 256 + threadIdx.x;
        int c = e >> 11, t = (e >> 9) & 3, l = (e >> 3) & 63, kp = e & 7;
        int j = 4 * c + (l >> 4);
        int n = t * 16 + (l & 15);
        float v = w[kp * 2048 + j * 64 + n];
        unsigned bits = __float_as_uint(v);
        float lo = v - __uint_as_float(bits & 0xFFFF0000u);
        whl[e]         = (ushort)(bits >> 16);
        whl[16384 + e] = (ushort)(__float_as_uint(lo) >> 16);
    }
}

__global__ __launch_bounds__(128) void k_gconv3(const float* __restrict__ xf,
                                                const int* __restrict__ cnt,
                                                const int* __restrict__ rlist,
                                                const ushort* __restrict__ whl,
                                                float* __restrict__ out) {
    __shared__ float vxl[2 * 4640];
    int lane = threadIdx.x & 63;
    int wv = threadIdx.x >> 6;
    int g = blockIdx.x * 2 + wv;
    int base = g * 16;
    if (base >= N_OUT) return;
    float* VX = vxl + wv * 4640;

    float4* z4 = (float4*)VX;
    float4 zz = make_float4(0.f, 0.f, 0.f, 0.f);
#pragma unroll
    for (int i = 0; i < 19; ++i) {
        int p = i * 64 + lane;
        if (p < 1156) z4[p] = zz;
    }

    int slot = lane >> 3, jq = lane & 7;
    int cv = cnt[base + (lane & 15)];
    const int* rbase = rlist + (size_t)base * CAP;
    int pkA = rbase[slot * CAP + jq];
    int pkB = rbase[(8 + slot) * CAP + jq];
    int pkC = rbase[slot * CAP + 8 + jq];
    int pkD = rbase[(8 + slot) * CAP + 8 + jq];

#pragma unroll
    for (int r = 0; r < 16; ++r) {
        int cr = __builtin_amdgcn_readlane(cv, r);
        if (cr > CAP) cr = CAP;
        if (cr == 0) continue;
        {
            int pk = __shfl(r < 8 ? pkA : pkB, (r & 7) * 8 + slot, 64);
            int idx = pk & 0x1FFFFF; if (idx > N_IN - 1) idx = N_IN - 1;
            int kp = (pk >> 21) & 7;
            const float4 x = *(const float4*)(xf + (size_t)idx * 32 + jq * 4);
            float* dst = VX + r * 289 + 36 * jq + kp;
            if (slot < cr) {
                atomicAdd(dst + 0,  x.x);
                atomicAdd(dst + 9,  x.y);
                atomicAdd(dst + 18, x.z);
                atomicAdd(dst + 27, x.w);
            }
        }
        if (cr > 8) {
            int pk = __shfl(r < 8 ? pkC : pkD, (r & 7) * 8 + slot, 64);
            int idx = pk & 0x1FFFFF; if (idx > N_IN - 1) idx = N_IN - 1;
            int kp = (pk >> 21) & 7;
            const float4 x = *(const float4*)(xf + (size_t)idx * 32 + jq * 4);
            float* dst = VX + r * 289 + 36 * jq + kp;
            if (8 + slot < cr) {
                atomicAdd(dst + 0,  x.x);
                atomicAdd(dst + 9,  x.y);
                atomicAdd(dst + 18, x.z);
                atomicAdd(dst + 27, x.w);
            }
        }
        if (cr > 16) {
            for (int p0 = 16; p0 < cr; p0 += 8) {
                int pp = p0 + slot; if (pp > cr - 1) pp = cr - 1;
                int pk = rlist[((size_t)base + r) * CAP + pp];
                int idx = pk & 0x1FFFFF; if (idx > N_IN - 1) idx = N_IN - 1;
                int kp = (pk >> 21) & 7;
                const float4 x = *(const float4*)(xf + (size_t)idx * 32 + jq * 4);
                float* dst = VX + r * 289 + 36 * jq + kp;
                if (p0 + slot < cr) {
                    atomicAdd(dst + 0,  x.x);
                    atomicAdd(dst + 9,  x.y);
                    atomicAdd(dst + 18, x.z);
                    atomicAdd(dst + 27, x.w);
                }
            }
        }
    }

    __builtin_amdgcn_sched_barrier(0);
    asm volatile("s_waitcnt lgkmcnt(0)" ::: "memory");
    __builtin_amdgcn_sched_barrier(0);

    int o = lane >> 4;
    int n16 = lane & 15;
    f32x4 zacc = {0.f, 0.f, 0.f, 0.f};
    f32x4 acc0 = zacc, acc1 = zacc, acc2 = zacc, acc3 = zacc;
    const short8* wh = (const short8*)whl;
    const short8* wl = wh + 2048;

#pragma unroll
    for (int c = 0; c < 8; ++c) {
        const float* src = VX + n16 * 289 + (4 * c + o) * 9;
        float a[8];
#pragma unroll
        for (int el = 0; el < 8; ++el) a[el] = src[el];
        short8 ahi, alo;
#pragma unroll
        for (int el = 0; el < 8; ++el) {
            unsigned b = __float_as_uint(a[el]);
            ahi[el] = (short)(b >> 16);
            float lo = a[el] - __uint_as_float(b & 0xFFFF0000u);
            alo[el] = (short)(__float_as_uint(lo) >> 16);
        }
#pragma unroll
        for (int t = 0; t < 4; ++t) {
            short8 bh = wh[(c * 4 + t) * 64 + lane];
            short8 bl = wl[(c * 4 + t) * 64 + lane];
            f32x4* pa = (t == 0) ? &acc0 : (t == 1) ? &acc1 : (t == 2) ? &acc2 : &acc3;
            *pa = __builtin_amdgcn_mfma_f32_16x16x32_bf16(ahi, bh, *pa, 0, 0, 0);
            *pa = __builtin_amdgcn_mfma_f32_16x16x32_bf16(alo, bh, *pa, 0, 0, 0);
            *pa = __builtin_amdgcn_mfma_f32_16x16x32_bf16(ahi, bl, *pa, 0, 0, 0);
        }
    }

#pragma unroll
    for (int t = 0; t < 4; ++t) {
        f32x4 a = (t == 0) ? acc0 : (t == 1) ? acc1 : (t == 2) ? acc2 : acc3;
#pragma unroll
        for (int reg = 0; reg < 4; ++reg)
            out[(size_t)(base + o * 4 + reg) * 64 + t * 16 + n16] = a[reg];
    }
}

// ============================== launch ==============================

extern "C" void kernel_launch(void* const* d_in, const int* in_sizes, int n_in,
                              void* d_out, int out_size, void* d_ws, size_t ws_size,
                              hipStream_t stream) {
    const float* in_feats = (const float*)d_in[0];
    const int*   offs     = (const int*)d_in[1];
    const int*   out_idx  = (const int*)d_in[2];
    const float* weight   = (const float*)d_in[3];
    const float* gamma    = (const float*)d_in[4];
    const float* beta     = (const float*)d_in[5];
    const float* context  = (const float*)d_in[6];
    const float* ctx_w    = (const float*)d_in[7];
    const int*   cond     = (const int*)d_in[8];
    float* out = (float*)d_out;

    int*   wsi = (int*)d_ws;
    float* wsf = (float*)d_ws;

    if (ws_size >= TA_NEED_BYTES) {
        // ---- tier-A: rank -> scan_a -> scan_c2 -> scatidx(+wpack) ->
        //      gconv14(+stats partials) -> statsred -> ctxprep -> norm ----
        int*    S      = wsi;                     // wsi[r] = start of row r
        ushort* whl    = (ushort*)(wsf + TA_WHL);
        int*    bsum   = wsi + TA_BSUM;
        float*  smalls = wsf + TA_SMALL;          // sums[64], sumsq[64], AB[128]
        int*    cnt    = wsi + TA_CNT;
        int*    idxg   = wsi + TA_IDXG;
        int*    pos0   = wsi + TA_POS;
        float*  part   = wsf + TA_PART;

        hipMemsetAsync(cnt, 0, (size_t)N_SCAN * 4, stream);

        k_rank<<<PT_BLOCKS, 256, 0, stream>>>(out_idx, cnt, pos0);
        k_scan_a<<<N_SBLK, 256, 0, stream>>>(cnt, S, bsum);
        k_scan_c2<<<N_SBLK, 256, 0, stream>>>(S, bsum);
        k_scatidx<<<PT_BLOCKS + 64, 256, 0, stream>>>(out_idx, offs, pos0, S,
                                                      weight, idxg, whl);
        k_gconv14<<<7813, 256, 0, stream>>>(in_feats, idxg, wsi, whl, out, part);

        k_statsred<<<128, 256, 0, stream>>>(part, smalls);
        k_ctxprep<<<1, 256, 0, stream>>>(context, ctx_w, smalls, smalls + 64,
                                         gamma, beta, cond, smalls + 128);
        k_norm<<<2048, 256, 0, stream>>>(out, smalls + 128);
    } else {
        // -------- tier-B: round-4 validated path --------
        int*    cnt    = wsi;
        ushort* whl    = (ushort*)(wsf + T1_WT);
        float*  smalls = wsf + T1_SMALL;
        int*    rlist  = wsi + T1_RLIST;

        hipMemsetAsync(cnt, 0, (size_t)N_OUT * 4, stream);
        hipMemsetAsync(smalls, 0, 128 * 4, stream);

        k_scat2<<<PT_BLOCKS + 64, 256, 0, stream>>>(out_idx, offs, weight, cnt, rlist, whl);
        k_gconv3<<<7813, 128, 0, stream>>>(in_feats, cnt, rlist, whl, out);

        k_stats<<<2048, 256, 0, stream>>>(out, smalls, smalls + 64);
        k_ctxprep<<<1, 256, 0, stream>>>(context, ctx_w, smalls, smalls + 64,
                                         gamma, beta, cond, smalls + 128);
        k_norm<<<2048, 256, 0, stream>>>(out, smalls + 128);
    }
}

// Round 24
// 403.687 us; speedup vs baseline: 1.0182x; 1.0044x over previous
//
#include <hip/hip_runtime.h>

#define N_IN 2000000
#define N_OUT 250000
#define C_IN 32
#define C_OUT 64
#define K_VOL 8
#define EPS 1e-5f
#define CAP 32

#define PT_BLOCKS 7813         // ceil(N_IN/256)
#define N_SCAN 250112          // 977*256
#define N_SBLK 977
#define NWAVE 31252            // 7813*4 (conv waves; valid groups < 31250)

typedef __attribute__((ext_vector_type(8))) short short8;
typedef __attribute__((ext_vector_type(4))) float f32x4;

// ======== tier-A workspace layout (int units) ========
#define TA_WHL    250368
#define TA_BSUM   266752
#define TA_SMALL  267776
#define TA_CNT    268288
#define TA_IDXG   1018400                                          // idxg[2M]
#define TA_POS    (TA_IDXG + N_IN)                                 // pos0[2M]
#define TA_PART   (TA_POS + N_IN)                                  // part[31252][128]
#define TA_NEED_BYTES ((size_t)(TA_PART + 128 * NWAVE) * 4)        // ~36 MB

// ======== tier-B (round-4 validated) workspace layout ========
#define T1_WT     250000
#define T1_SMALL  266384
#define T1_RLIST  266768
#define T1_NEED_BYTES ((size_t)(T1_RLIST + N_OUT * CAP) * 4)

// ==================== tier-A: single-atomic-pass counting sort ====================

__global__ __launch_bounds__(256) void k_rank(const int* __restrict__ out_idx,
                                              int* __restrict__ cnt,
                                              int* __restrict__ pos0) {
    int i = blockIdx.x * 256 + threadIdx.x;
    if (i < N_IN) pos0[i] = atomicAdd(&cnt[out_idx[i]], 1);
}

__global__ __launch_bounds__(256) void k_scan_a(const int* __restrict__ cnt,
                                                int* __restrict__ S,
                                                int* __restrict__ bsum) {
    __shared__ int sh[256];
    int t = threadIdx.x;
    int g = blockIdx.x * 256 + t;
    int v = cnt[g];
    sh[t] = v;
    __syncthreads();
#pragma unroll
    for (int off = 1; off < 256; off <<= 1) {
        int a = (t >= off) ? sh[t - off] : 0;
        __syncthreads();
        sh[t] += a;
        __syncthreads();
    }
    S[g] = sh[t] - v;              // exclusive within block
    if (t == 255) bsum[blockIdx.x] = sh[255];
}

// scan_b folded in: each block sums bsum[j < blockIdx] (L2-hot) via tree-reduce.
__global__ __launch_bounds__(256) void k_scan_c2(int* __restrict__ S,
                                                 const int* __restrict__ bsum) {
    __shared__ int red[256];
    int t = threadIdx.x, bid = blockIdx.x;
    int acc = 0;
    for (int j = t; j < bid; j += 256) acc += bsum[j];
    red[t] = acc;
    __syncthreads();
#pragma unroll
    for (int off = 128; off > 0; off >>= 1) {
        if (t < off) red[t] += red[t + off];
        __syncthreads();
    }
    S[bid * 256 + t] += red[0];
}

// Index-only scatter (L2-absorbed 4B writes) + fused weight hi/lo pack tail.
__global__ __launch_bounds__(256) void k_scatidx(const int* __restrict__ out_idx,
                                                 const int* __restrict__ offs,
                                                 const int* __restrict__ pos0,
                                                 const int* __restrict__ S,
                                                 const float* __restrict__ w,
                                                 int* __restrict__ idxg,
                                                 ushort* __restrict__ whl) {
    int b = blockIdx.x;
    if (b < PT_BLOCKS) {
        int i = b * 256 + threadIdx.x;
        if (i >= N_IN) return;
        int o = out_idx[i];
        int tag = offs[i] | ((o & 31) << 3);
        idxg[S[o] + pos0[i]] = i | (tag << 21);
    } else {
        int e = (b - PT_BLOCKS) * 256 + threadIdx.x;   // 0..16383
        int c = e >> 11, t = (e >> 9) & 3, l = (e >> 3) & 63, kp = e & 7;
        int j = 4 * c + (l >> 4);
        int n = t * 16 + (l & 15);
        float v = w[kp * 2048 + j * 64 + n];
        unsigned bits = __float_as_uint(v);
        float lo = v - __uint_as_float(bits & 0xFFFF0000u);
        whl[e]         = (ushort)(bits >> 16);
        whl[16384 + e] = (ushort)(__float_as_uint(lo) >> 16);
    }
}

// ==================== tier-A: gconv12 + fused stats, wave-major partials ====================
// Hot loop byte-identical to validated gconv12; epilogue writes part[g][128]
// (one contiguous 512B block per wave -> full-line write combining).
__global__ __launch_bounds__(256) void k_gconv15(const float* __restrict__ xf,
                                                 const int* __restrict__ idxg,
                                                 const int* __restrict__ Sarr,
                                                 const ushort* __restrict__ whl,
                                                 float* __restrict__ out,
                                                 float* __restrict__ part) {
    __shared__ float vxl[4 * 3104];
    int lane = threadIdx.x & 63;
    int wv = threadIdx.x >> 6;
    int g = blockIdx.x * 4 + wv;
    int base = g * 8;
    if (base >= N_OUT) return;
    float* VX = vxl + wv * 3104;
    short* XT = (short*)VX;   // 2 staging buffers of 3104 shorts each (alias VX head)

    int s = Sarr[base];
    int e = Sarr[base + 8];
    int slot = lane >> 3, jq = lane & 7;

    int tgt4[4];
#pragma unroll
    for (int m = 0; m < 4; ++m) {
        int bin0 = m * 16 + (lane & 15);
        tgt4[m] = (((base + (bin0 >> 3)) & 31) << 3) | (bin0 & 7);
    }

    f32x4 acc1[4][2];
#pragma unroll
    for (int m = 0; m < 4; ++m)
#pragma unroll
        for (int n = 0; n < 2; ++n)
            acc1[m][n] = (f32x4){0.f, 0.f, 0.f, 0.f};

    auto LOADBLK = [&](int p0, float4* xvv, int* tvv) {
        int pk[4];
#pragma unroll
        for (int q = 0; q < 4; ++q) {
            int p = p0 + q * 8 + slot;
            int pc = p < e ? p : e - 1;
            pk[q] = idxg[pc];                       // coalesced 4B (broadcast in group)
        }
#pragma unroll
        for (int q = 0; q < 4; ++q) {
            int p = p0 + q * 8 + slot;
            int idx = pk[q] & 0x1FFFFF;
            tvv[q] = (pk[q] >> 21) & 0xFF;
            xvv[q] = *(const float4*)(xf + (size_t)idx * 32 + jq * 4);  // full 128B line/group
            if (p >= e) xvv[q] = make_float4(0.f, 0.f, 0.f, 0.f);       // pad adds 0
        }
    };
    auto STAGE = [&](int bb, const float4* xvv, const int* tvv) {
        short* Xh = XT + bb * 3104;
        short* Xl = Xh + 1536;
        unsigned char* TGb = (unsigned char*)(Xh + 3072);
#pragma unroll
        for (int q = 0; q < 4; ++q) {
            int wpos = ((q ^ (jq & 3)) << 3) + slot;   // XOR block swizzle
#pragma unroll
            for (int i = 0; i < 4; ++i) {
                float v = (i == 0) ? xvv[q].x : (i == 1) ? xvv[q].y
                         : (i == 2) ? xvv[q].z : xvv[q].w;
                unsigned b = __float_as_uint(v);
                float lo = v - __uint_as_float(b & 0xFFFF0000u);
                int ch = 4 * jq + i;
                Xh[ch * 48 + wpos] = (short)(b >> 16);
                Xl[ch * 48 + wpos] = (short)(__float_as_uint(lo) >> 16);
            }
            if (jq == 0) TGb[q * 8 + slot] = (unsigned char)tvv[q];
        }
    };

    if (e > s) {
        float4 xvA[4], xvB[4], xvC[4];
        int tvA[4], tvB[4], tvC[4];
        int nIt = (e - s + 31) >> 5;
        LOADBLK(s, xvA, tvA);                    // it 0
        LOADBLK(s + 32, xvB, tvB);               // it 1 (clamped if absent)
        STAGE(0, xvA, tvA);
        for (int it = 0; it < nIt; ++it) {
            int cur = it & 1;
            if (it + 2 < nIt) LOADBLK(s + (it + 2) * 32, xvC, tvC);  // 2-deep prefetch

            asm volatile("s_waitcnt lgkmcnt(0)" ::: "memory");  // stage(cur) drained

            const short* Xh = XT + cur * 3104;
            const short* Xl = Xh + 1536;
            const unsigned char* TGb = (const unsigned char*)(Xh + 3072);
            unsigned long long t8 = *(const unsigned long long*)(TGb + 8 * (lane >> 4));
            int tgv[8];
#pragma unroll
            for (int e2 = 0; e2 < 8; ++e2) tgv[e2] = (int)((t8 >> (8 * e2)) & 0xFF);
            short8 bhf[2], blf[2];
#pragma unroll
            for (int n = 0; n < 2; ++n) {
                int ch = n * 16 + (lane & 15);
                int off = ch * 48 + 8 * ((lane >> 4) ^ ((ch >> 2) & 3));
                bhf[n] = *(const short8*)(Xh + off);
                blf[n] = *(const short8*)(Xl + off);
            }

            // ---- issue next-buffer STAGE writes BEFORE MFMA (overlap) ----
            if (it + 1 < nIt) STAGE(cur ^ 1, xvB, tvB);
            __builtin_amdgcn_sched_barrier(0);   // pin: writes issue before MFMA

#pragma unroll
            for (int m = 0; m < 4; ++m) {
                short8 ah;
#pragma unroll
                for (int e2 = 0; e2 < 8; ++e2)
                    ah[e2] = (tgv[e2] == tgt4[m]) ? (short)0x3F80 : (short)0;
#pragma unroll
                for (int n = 0; n < 2; ++n) {
                    acc1[m][n] = __builtin_amdgcn_mfma_f32_16x16x32_bf16(ah, bhf[n], acc1[m][n], 0, 0, 0);
                    acc1[m][n] = __builtin_amdgcn_mfma_f32_16x16x32_bf16(ah, blf[n], acc1[m][n], 0, 0, 0);
                }
            }

            if (it + 1 < nIt) {
#pragma unroll
                for (int q = 0; q < 4; ++q) { xvB[q] = xvC[q]; tvB[q] = tvC[q]; }
            }
        }
    }

    asm volatile("s_waitcnt lgkmcnt(0)" ::: "memory");

    // ---- deposit XS -> VX[r*289 + ch*9 + kp] (r in 0..7, full coverage) ----
#pragma unroll
    for (int m = 0; m < 4; ++m)
#pragma unroll
        for (int n = 0; n < 2; ++n)
#pragma unroll
            for (int reg = 0; reg < 4; ++reg) {
                int bin = m * 16 + (lane >> 4) * 4 + reg;     // 0..63
                VX[(bin >> 3) * 289 + (n * 16 + (lane & 15)) * 9 + (bin & 7)] = acc1[m][n][reg];
            }

    __builtin_amdgcn_sched_barrier(0);
    asm volatile("s_waitcnt lgkmcnt(0)" ::: "memory");
    __builtin_amdgcn_sched_barrier(0);

    // ---- GEMM-2: out[8x64] = XS[8x256] @ W[256x64], split-bf16, M padded to 16 ----
    int o = lane >> 4;
    int n16 = lane & 15;
    f32x4 zacc = {0.f, 0.f, 0.f, 0.f};
    f32x4 acc0 = zacc, accA = zacc, accB = zacc, accC = zacc;
    const short8* wh = (const short8*)whl;
    const short8* wl = wh + 2048;

#pragma unroll
    for (int c = 0; c < 8; ++c) {
        float a[8];
        if (n16 < 8) {
            const float* src = VX + n16 * 289 + (4 * c + o) * 9;
#pragma unroll
            for (int el = 0; el < 8; ++el) a[el] = src[el];
        } else {
#pragma unroll
            for (int el = 0; el < 8; ++el) a[el] = 0.f;
        }
        short8 ahi, alo;
#pragma unroll
        for (int el = 0; el < 8; ++el) {
            unsigned b = __float_as_uint(a[el]);
            ahi[el] = (short)(b >> 16);
            float lo = a[el] - __uint_as_float(b & 0xFFFF0000u);
            alo[el] = (short)(__float_as_uint(lo) >> 16);
        }
#pragma unroll
        for (int t = 0; t < 4; ++t) {
            short8 bh = wh[(c * 4 + t) * 64 + lane];
            short8 bl = wl[(c * 4 + t) * 64 + lane];
            f32x4* pa = (t == 0) ? &acc0 : (t == 1) ? &accA : (t == 2) ? &accB : &accC;
            *pa = __builtin_amdgcn_mfma_f32_16x16x32_bf16(ahi, bh, *pa, 0, 0, 0);
            *pa = __builtin_amdgcn_mfma_f32_16x16x32_bf16(alo, bh, *pa, 0, 0, 0);
            *pa = __builtin_amdgcn_mfma_f32_16x16x32_bf16(ahi, bl, *pa, 0, 0, 0);
        }
    }

    if (o < 2) {                                   // D rows 0..7 only
#pragma unroll
        for (int t = 0; t < 4; ++t) {
            f32x4 a = (t == 0) ? acc0 : (t == 1) ? accA : (t == 2) ? accB : accC;
#pragma unroll
            for (int reg = 0; reg < 4; ++reg)
                out[(size_t)(base + o * 4 + reg) * 64 + t * 16 + n16] = a[reg];
        }
    }

    // ---- fused channel stats (rows 8-15 are exactly 0), wave-major write ----
    float sv[4], qv[4];
#pragma unroll
    for (int t = 0; t < 4; ++t) {
        f32x4 a = (t == 0) ? acc0 : (t == 1) ? accA : (t == 2) ? accB : accC;
        float sa = 0.f, qa = 0.f;
#pragma unroll
        for (int reg = 0; reg < 4; ++reg) {
            sa += a[reg];
            qa = fmaf(a[reg], a[reg], qa);
        }
        sv[t] = sa; qv[t] = qa;
    }
#pragma unroll
    for (int t = 0; t < 4; ++t) {
        sv[t] += __shfl_xor(sv[t], 16, 64);
        sv[t] += __shfl_xor(sv[t], 32, 64);
        qv[t] += __shfl_xor(qv[t], 16, 64);
        qv[t] += __shfl_xor(qv[t], 32, 64);
    }
    if (lane < 16) {
        float* pg = part + (size_t)g * 128;       // contiguous 512B per wave
#pragma unroll
        for (int t = 0; t < 4; ++t) {
            pg[t * 16 + lane]      = sv[t];
            pg[64 + t * 16 + lane] = qv[t];
        }
    }
}

// ==================== tier-A: partial reduce, stride-128 reads (L2-absorbed) ====================
__global__ __launch_bounds__(256) void k_statsred2(const float* __restrict__ part,
                                                   float* __restrict__ smalls) {
    __shared__ float red[256];
    int c = blockIdx.x;                 // 0..127 (0-63 sums, 64-127 sumsq)
    int t = threadIdx.x;
    float s = 0.f;
    for (int g = t; g < 31250; g += 256) s += part[(size_t)g * 128 + c];
    red[t] = s;
    __syncthreads();
#pragma unroll
    for (int off = 128; off > 0; off >>= 1) {
        if (t < off) red[t] += red[t + off];
        __syncthreads();
    }
    if (t == 0) smalls[c] = red[0];
}

// ==================== shared post-passes ====================

__global__ __launch_bounds__(256) void k_stats(const float* __restrict__ out,
                                               float* __restrict__ sums,
                                               float* __restrict__ sumsq) {
    int t = threadIdx.x;
    long stride = (long)gridDim.x * 256;
    float s = 0.f, q = 0.f;
    for (long i = (long)blockIdx.x * 256 + t; i < (long)N_OUT * C_OUT; i += stride) {
        float v = out[i];
        s += v;
        q = fmaf(v, v, q);
    }
    __shared__ float ls[256], lq[256];
    ls[t] = s; lq[t] = q;
    __syncthreads();
    if (t < 64) {
        s = ls[t] + ls[t + 64] + ls[t + 128] + ls[t + 192];
        q = lq[t] + lq[t + 64] + lq[t + 128] + lq[t + 192];
        atomicAdd(&sums[t], s);
        atomicAdd(&sumsq[t], q);
    }
}

__global__ __launch_bounds__(256) void k_ctxprep(const float* __restrict__ context,
                                                 const float* __restrict__ ctx_w,
                                                 const float* __restrict__ sums,
                                                 const float* __restrict__ sumsq,
                                                 const float* __restrict__ gamma,
                                                 const float* __restrict__ beta,
                                                 const int* __restrict__ cond,
                                                 float* __restrict__ AB) {
    __shared__ float part[256];
    __shared__ float ctxv[128];
    int t = threadIdx.x;
    int col = t & 127, half = t >> 7;
    float s = 0.f;
    for (int r = half * 128; r < half * 128 + 128; ++r)
        s = fmaf(context[r], ctx_w[r * 128 + col], s);
    part[t] = s;
    __syncthreads();
    if (t < 128) ctxv[t] = part[t] + part[t + 128];
    __syncthreads();
    if (t < 64) {
        float mean = sums[t] * (1.f / N_OUT);
        float var  = sumsq[t] * (1.f / N_OUT) - mean * mean;
        float inv  = rsqrtf(var + EPS);
        int cd = cond[0];
        float gm = gamma[cd * C_OUT + t], bt = beta[cd * C_OUT + t];
        float sc = 1.f + ctxv[t];
        float sh = ctxv[64 + t];
        AB[t]      = inv * gm * sc;
        AB[64 + t] = (bt - mean * inv * gm) * sc + sh;
    }
}

__global__ __launch_bounds__(256) void k_norm(float* __restrict__ out,
                                              const float* __restrict__ AB) {
    __shared__ float4 lA[16], lB[16];
    int t = threadIdx.x;
    if (t < 16) {
        lA[t] = ((const float4*)AB)[t];
        lB[t] = ((const float4*)AB)[16 + t];
    }
    __syncthreads();
    const long total4 = (long)N_OUT * C_OUT / 4;
    long stride = (long)gridDim.x * 256;
    for (long i = (long)blockIdx.x * 256 + t; i < total4; i += stride) {
        float4 v = ((float4*)out)[i];
        float4 a = lA[i & 15], b = lB[i & 15];
        v.x = fmaxf(fmaf(v.x, a.x, b.x), 0.f);
        v.y = fmaxf(fmaf(v.y, a.y, b.y), 0.f);
        v.z = fmaxf(fmaf(v.z, a.z, b.z), 0.f);
        v.w = fmaxf(fmaf(v.w, a.w, b.w), 0.f);
        ((float4*)out)[i] = v;
    }
}

// ==================== tier-B (round-4 validated path) ====================

__global__ __launch_bounds__(256) void k_scat2(const int* __restrict__ out_idx,
                                               const int* __restrict__ offs,
                                               const float* __restrict__ w,
                                               int* __restrict__ cnt,
                                               int* __restrict__ rlist,
                                               ushort* __restrict__ whl) {
    int b = blockIdx.x;
    if (b < PT_BLOCKS) {
        int i = b * 256 + threadIdx.x;
        if (i < N_IN) {
            int o = out_idx[i];
            int pos = atomicAdd(&cnt[o], 1);
            if (pos < CAP) rlist[o * CAP + pos] = i | (offs[i] << 21);
        }
    } else {
        int e = (b - PT_BLOCKS) * 256 + threadIdx.x;
        int c = e >> 11, t = (e >> 9) & 3, l = (e >> 3) & 63, kp = e & 7;
        int j = 4 * c + (l >> 4);
        int n = t * 16 + (l & 15);
        float v = w[kp * 2048 + j * 64 + n];
        unsigned bits = __float_as_uint(v);
        float lo = v - __uint_as_float(bits & 0xFFFF0000u);
        whl[e]         = (ushort)(bits >> 16);
        whl[16384 + e] = (ushort)(__float_as_uint(lo) >> 16);
    }
}

__global__ __launch_bounds__(128) void k_gconv3(const float* __restrict__ xf,
                                                const int* __restrict__ cnt,
                                                const int* __restrict__ rlist,
                                                const ushort* __restrict__ whl,
                                                float* __restrict__ out) {
    __shared__ float vxl[2 * 4640];
    int lane = threadIdx.x & 63;
    int wv = threadIdx.x >> 6;
    int g = blockIdx.x * 2 + wv;
    int base = g * 16;
    if (base >= N_OUT) return;
    float* VX = vxl + wv * 4640;

    float4* z4 = (float4*)VX;
    float4 zz = make_float4(0.f, 0.f, 0.f, 0.f);
#pragma unroll
    for (int i = 0; i < 19; ++i) {
        int p = i * 64 + lane;
        if (p < 1156) z4[p] = zz;
    }

    int slot = lane >> 3, jq = lane & 7;
    int cv = cnt[base + (lane & 15)];
    const int* rbase = rlist + (size_t)base * CAP;
    int pkA = rbase[slot * CAP + jq];
    int pkB = rbase[(8 + slot) * CAP + jq];
    int pkC = rbase[slot * CAP + 8 + jq];
    int pkD = rbase[(8 + slot) * CAP + 8 + jq];

#pragma unroll
    for (int r = 0; r < 16; ++r) {
        int cr = __builtin_amdgcn_readlane(cv, r);
        if (cr > CAP) cr = CAP;
        if (cr == 0) continue;
        {
            int pk = __shfl(r < 8 ? pkA : pkB, (r & 7) * 8 + slot, 64);
            int idx = pk & 0x1FFFFF; if (idx > N_IN - 1) idx = N_IN - 1;
            int kp = (pk >> 21) & 7;
            const float4 x = *(const float4*)(xf + (size_t)idx * 32 + jq * 4);
            float* dst = VX + r * 289 + 36 * jq + kp;
            if (slot < cr) {
                atomicAdd(dst + 0,  x.x);
                atomicAdd(dst + 9,  x.y);
                atomicAdd(dst + 18, x.z);
                atomicAdd(dst + 27, x.w);
            }
        }
        if (cr > 8) {
            int pk = __shfl(r < 8 ? pkC : pkD, (r & 7) * 8 + slot, 64);
            int idx = pk & 0x1FFFFF; if (idx > N_IN - 1) idx = N_IN - 1;
            int kp = (pk >> 21) & 7;
            const float4 x = *(const float4*)(xf + (size_t)idx * 32 + jq * 4);
            float* dst = VX + r * 289 + 36 * jq + kp;
            if (8 + slot < cr) {
                atomicAdd(dst + 0,  x.x);
                atomicAdd(dst + 9,  x.y);
                atomicAdd(dst + 18, x.z);
                atomicAdd(dst + 27, x.w);
            }
        }
        if (cr > 16) {
            for (int p0 = 16; p0 < cr; p0 += 8) {
                int pp = p0 + slot; if (pp > cr - 1) pp = cr - 1;
                int pk = rlist[((size_t)base + r) * CAP + pp];
                int idx = pk & 0x1FFFFF; if (idx > N_IN - 1) idx = N_IN - 1;
                int kp = (pk >> 21) & 7;
                const float4 x = *(const float4*)(xf + (size_t)idx * 32 + jq * 4);
                float* dst = VX + r * 289 + 36 * jq + kp;
                if (p0 + slot < cr) {
                    atomicAdd(dst + 0,  x.x);
                    atomicAdd(dst + 9,  x.y);
                    atomicAdd(dst + 18, x.z);
                    atomicAdd(dst + 27, x.w);
                }
            }
        }
    }

    __builtin_amdgcn_sched_barrier(0);
    asm volatile("s_waitcnt lgkmcnt(0)" ::: "memory");
    __builtin_amdgcn_sched_barrier(0);

    int o = lane >> 4;
    int n16 = lane & 15;
    f32x4 zacc = {0.f, 0.f, 0.f, 0.f};
    f32x4 acc0 = zacc, acc1 = zacc, acc2 = zacc, acc3 = zacc;
    const short8* wh = (const short8*)whl;
    const short8* wl = wh + 2048;

#pragma unroll
    for (int c = 0; c < 8; ++c) {
        const float* src = VX + n16 * 289 + (4 * c + o) * 9;
        float a[8];
#pragma unroll
        for (int el = 0; el < 8; ++el) a[el] = src[el];
        short8 ahi, alo;
#pragma unroll
        for (int el = 0; el < 8; ++el) {
            unsigned b = __float_as_uint(a[el]);
            ahi[el] = (short)(b >> 16);
            float lo = a[el] - __uint_as_float(b & 0xFFFF0000u);
            alo[el] = (short)(__float_as_uint(lo) >> 16);
        }
#pragma unroll
        for (int t = 0; t < 4; ++t) {
            short8 bh = wh[(c * 4 + t) * 64 + lane];
            short8 bl = wl[(c * 4 + t) * 64 + lane];
            f32x4* pa = (t == 0) ? &acc0 : (t == 1) ? &acc1 : (t == 2) ? &acc2 : &acc3;
            *pa = __builtin_amdgcn_mfma_f32_16x16x32_bf16(ahi, bh, *pa, 0, 0, 0);
            *pa = __builtin_amdgcn_mfma_f32_16x16x32_bf16(alo, bh, *pa, 0, 0, 0);
            *pa = __builtin_amdgcn_mfma_f32_16x16x32_bf16(ahi, bl, *pa, 0, 0, 0);
        }
    }

#pragma unroll
    for (int t = 0; t < 4; ++t) {
        f32x4 a = (t == 0) ? acc0 : (t == 1) ? acc1 : (t == 2) ? acc2 : acc3;
#pragma unroll
        for (int reg = 0; reg < 4; ++reg)
            out[(size_t)(base + o * 4 + reg) * 64 + t * 16 + n16] = a[reg];
    }
}

// ============================== launch ==============================

extern "C" void kernel_launch(void* const* d_in, const int* in_sizes, int n_in,
                              void* d_out, int out_size, void* d_ws, size_t ws_size,
                              hipStream_t stream) {
    const float* in_feats = (const float*)d_in[0];
    const int*   offs     = (const int*)d_in[1];
    const int*   out_idx  = (const int*)d_in[2];
    const float* weight   = (const float*)d_in[3];
    const float* gamma    = (const float*)d_in[4];
    const float* beta     = (const float*)d_in[5];
    const float* context  = (const float*)d_in[6];
    const float* ctx_w    = (const float*)d_in[7];
    const int*   cond     = (const int*)d_in[8];
    float* out = (float*)d_out;

    int*   wsi = (int*)d_ws;
    float* wsf = (float*)d_ws;

    if (ws_size >= TA_NEED_BYTES) {
        // ---- tier-A: rank -> scan_a -> scan_c2 -> scatidx(+wpack) ->
        //      gconv15(+wave-major stats partials) -> statsred2 -> ctxprep -> norm ----
        int*    S      = wsi;                     // wsi[r] = start of row r
        ushort* whl    = (ushort*)(wsf + TA_WHL);
        int*    bsum   = wsi + TA_BSUM;
        float*  smalls = wsf + TA_SMALL;          // sums[64], sumsq[64], AB[128]
        int*    cnt    = wsi + TA_CNT;
        int*    idxg   = wsi + TA_IDXG;
        int*    pos0   = wsi + TA_POS;
        float*  part   = wsf + TA_PART;

        hipMemsetAsync(cnt, 0, (size_t)N_SCAN * 4, stream);

        k_rank<<<PT_BLOCKS, 256, 0, stream>>>(out_idx, cnt, pos0);
        k_scan_a<<<N_SBLK, 256, 0, stream>>>(cnt, S, bsum);
        k_scan_c2<<<N_SBLK, 256, 0, stream>>>(S, bsum);
        k_scatidx<<<PT_BLOCKS + 64, 256, 0, stream>>>(out_idx, offs, pos0, S,
                                                      weight, idxg, whl);
        k_gconv15<<<7813, 256, 0, stream>>>(in_feats, idxg, wsi, whl, out, part);

        k_statsred2<<<128, 256, 0, stream>>>(part, smalls);
        k_ctxprep<<<1, 256, 0, stream>>>(context, ctx_w, smalls, smalls + 64,
                                         gamma, beta, cond, smalls + 128);
        k_norm<<<2048, 256, 0, stream>>>(out, smalls + 128);
    } else {
        // -------- tier-B: round-4 validated path --------
        int*    cnt    = wsi;
        ushort* whl    = (ushort*)(wsf + T1_WT);
        float*  smalls = wsf + T1_SMALL;
        int*    rlist  = wsi + T1_RLIST;

        hipMemsetAsync(cnt, 0, (size_t)N_OUT * 4, stream);
        hipMemsetAsync(smalls, 0, 128 * 4, stream);

        k_scat2<<<PT_BLOCKS + 64, 256, 0, stream>>>(out_idx, offs, weight, cnt, rlist, whl);
        k_gconv3<<<7813, 128, 0, stream>>>(in_feats, cnt, rlist, whl, out);

        k_stats<<<2048, 256, 0, stream>>>(out, smalls, smalls + 64);
        k_ctxprep<<<1, 256, 0, stream>>>(context, ctx_w, smalls, smalls + 64,
                                         gamma, beta, cond, smalls + 128);
        k_norm<<<2048, 256, 0, stream>>>(out, smalls + 128);
    }
}